// Round 6
// baseline (603.226 us; speedup 1.0000x reference)
//
#include <hip/hip_runtime.h>

// ---------------------------------------------------------------------------
// MHSelfAttention (Transformer-XL relative shift), MI355X gfx950
// B=4 L=1536 D=768 H=8 DQK=64 DV=96 NPF=96
// logits[b,h,i,j] = (Q*s+rwb)[i].K[j] + (Q*s+rrb)[i].rK[j-i+L-1]
// ROUND 6: inputs f32 (dict order, verified), OUTPUT F32 (reference returns
// float32 — the "(bf16)" in the test label is the threshold mode, not the
// readback dtype). MFMA pipeline (R3), validated against scalar pipeline (R4):
// both computed identical values; only the output encoding was wrong.
// ---------------------------------------------------------------------------

typedef unsigned short u16;
typedef unsigned int   u32;

typedef __bf16 bf16x8_t __attribute__((ext_vector_type(8)));
typedef unsigned short u16x8_t __attribute__((ext_vector_type(8)));
typedef float f32x4_t __attribute__((ext_vector_type(4)));

union Frag { u16x8_t u; bf16x8_t b; };

__device__ __forceinline__ float bf2f(u16 v){
  union { u32 i; float f; } c; c.i = ((u32)v) << 16; return c.f;
}
__device__ __forceinline__ u16 f2bf(float f){
  union { float f; u32 i; } c; c.f = f;
  u32 r = c.i + 0x7FFFu + ((c.i >> 16) & 1u);
  return (u16)(r >> 16);
}

#define LQ   1536
#define NPOS 3071   // 2L-1
#define NPOSP 3072  // row stride (row 3071 zeroed; indices j-i+1535 <= 3070)

// ---------------------------------------------------------------------------
// K0a: x (f32) -> bf16 staging. grid 4608 x 256, 4 elems/thread
// ---------------------------------------------------------------------------
__global__ void cvt_x(const float* __restrict__ x, u16* __restrict__ xb)
{
  int gid = blockIdx.x * 256 + threadIdx.x;
  float4 v = ((const float4*)x)[gid];
  xb[4*gid+0] = f2bf(v.x); xb[4*gid+1] = f2bf(v.y);
  xb[4*gid+2] = f2bf(v.z); xb[4*gid+3] = f2bf(v.w);
}

// ---------------------------------------------------------------------------
// K0b: weight transposes -> K-major (N x K) bf16 for MFMA B-fragment loads
// grid 2560 x 256. cols 0..1791 -> WtQKV (Q|K|V), 1792.. -> WtOut
// ---------------------------------------------------------------------------
__global__ void transpose_w(const float* __restrict__ Qw_, const float* __restrict__ Kw_,
                            const float* __restrict__ Vw_, const float* __restrict__ Ow_,
                            u16* __restrict__ WtQKV, u16* __restrict__ WtOut)
{
  int c = blockIdx.x;
  if (c < 1792) {
    const float* src; int cl, stride;
    if (c < 512)       { src = Qw_; cl = c;        stride = 512; }
    else if (c < 1024) { src = Kw_; cl = c - 512;  stride = 512; }
    else               { src = Vw_; cl = c - 1024; stride = 768; }
    for (int k = threadIdx.x; k < 768; k += 256)
      WtQKV[(size_t)c*768 + k] = f2bf(src[(size_t)k*stride + cl]);
  } else {
    int c2 = c - 1792;
    for (int k = threadIdx.x; k < 768; k += 256)
      WtOut[(size_t)c2*768 + k] = f2bf(Ow_[(size_t)k*768 + c2]);
  }
}

// ---------------------------------------------------------------------------
// K1: per-gamma-feature max over |pos| in [0,1535]   (16 blocks x 256)
// mean=96(f+1), stddev=48 -> conc=4(f+1)^2, rate=(f+1)/24
// ---------------------------------------------------------------------------
__global__ void gamma_max_k(float* __restrict__ gmax)
{
  int f = blockIdx.x;                 // 0..15
  float fi   = (float)(f + 1);
  float conc = 4.0f * fi * fi;
  float rate = fi / 24.0f;
  float c1   = conc - 1.0f;
  float lognorm = lgammaf(conc) - conc * logf(rate);
  float mx = 0.0f;
  for (int x = threadIdx.x; x < 1536; x += 256) {
    float xf = (float)x;
    float lu = (x == 0) ? -INFINITY : (c1 * logf(xf) - rate * xf);
    float p  = expf(lu - lognorm) + 1e-8f;
    mx = fmaxf(mx, p);
  }
  for (int d = 1; d < 64; d <<= 1) mx = fmaxf(mx, __shfl_xor(mx, d, 64));
  __shared__ float red[4];
  if ((threadIdx.x & 63) == 0) red[threadIdx.x >> 6] = mx;
  __syncthreads();
  if (threadIdx.x == 0)
    gmax[f] = fmaxf(fmaxf(red[0], red[1]), fmaxf(red[2], red[3]));
}

// ---------------------------------------------------------------------------
// K2: rK[h][k][d] = sum_f pe_feats(k)[f] * relKw[f][h*64+d], bf16 (8,3072,64)
// relKw f32 (96 x 512). grid 3072 x 256; block 3071 zeroes the pad row.
// ---------------------------------------------------------------------------
__global__ void rk_k(const float* __restrict__ gmax,
                     const float* __restrict__ relKw, u16* __restrict__ rK)
{
  int k = blockIdx.x;
  int t = threadIdx.x;
  if (k == NPOS) {   // pad row -> zero (never read; keeps stride uniform)
    for (int c = t; c < 512; c += 256)
      rK[(((size_t)(c >> 6))*NPOSP + NPOS)*64 + (c & 63)] = 0;
    return;
  }
  __shared__ float feats[96];
  float pos = (float)(k - (LQ - 1));
  float x   = fabsf(pos);
  float sgn = (float)((pos > 0.0f) - (pos < 0.0f));
  if (t < 96) {
    int tb = (t < 48) ? t : t - 48;   // 48 not a power of two; & is wrong
    float val;
    if (tb < 16) {
      float max_range = log2f((float)LQ);
      float hl = exp2f(3.0f + (float)tb * (max_range - 3.0f) / 15.0f);
      val = expf(-0.69314718056f / hl * x);
    } else if (tb < 32) {
      int i = tb - 16;
      float width = (float)(1u << (i + 1)) - 1.0f;
      val = (width > x) ? 1.0f : 0.0f;
    } else {
      int i = tb - 32;
      float fi   = (float)(i + 1);
      float conc = 4.0f * fi * fi;
      float rate = fi / 24.0f;
      float lognorm = lgammaf(conc) - conc * logf(rate);
      float lu = (x == 0.0f) ? -INFINITY : ((conc - 1.0f) * logf(x) - rate * x);
      float p  = expf(lu - lognorm) + 1e-8f;
      val = p / gmax[i];
    }
    feats[t] = (t < 48) ? val : sgn * val;
  }
  __syncthreads();
  for (int c = t; c < 512; c += 256) {
    float acc = 0.0f;
    #pragma unroll 8
    for (int f = 0; f < 96; ++f) acc += feats[f] * relKw[(size_t)f*512 + c];
    rK[(((size_t)(c >> 6))*NPOSP + k)*64 + (c & 63)] = f2bf(acc);
  }
}

// ---------------------------------------------------------------------------
// K4: fused QKV projection GEMM (M=6144, N=1792, K=768), MFMA 16x16x32 bf16
// A = xb (token,k), B = WtQKV (c,k). Epilogue: Q*0.125 / K / V(T).
// grid (28, 96) x 256
// ---------------------------------------------------------------------------
__global__ __launch_bounds__(256) void qkv_gemm(
    const u16* __restrict__ xb, const u16* __restrict__ Wt,
    u16* __restrict__ Qb, u16* __restrict__ Kc, u16* __restrict__ Vt)
{
  const int n0 = blockIdx.x * 64;
  const int m0 = blockIdx.y * 64;
  const int tid = threadIdx.x, w = tid >> 6, lane = tid & 63, q = lane >> 4, s = lane & 15;

  const u16* arow = xb + (size_t)(m0 + 16*w + s) * 768;
  const u16* brow = Wt + (size_t)n0 * 768;

  const f32x4_t fz = {0.f, 0.f, 0.f, 0.f};
  f32x4_t acc[4] = {fz, fz, fz, fz};

  for (int kk = 0; kk < 768; kk += 32) {
    Frag af; af.u = *(const u16x8_t*)(arow + kk + q*8);
    #pragma unroll
    for (int ns = 0; ns < 4; ++ns) {
      Frag bf; bf.u = *(const u16x8_t*)(brow + (size_t)(ns*16 + s)*768 + kk + q*8);
      acc[ns] = __builtin_amdgcn_mfma_f32_16x16x32_bf16(af.b, bf.b, acc[ns], 0, 0, 0);
    }
  }

  #pragma unroll
  for (int ns = 0; ns < 4; ++ns) {
    int c = n0 + ns*16 + s;
    #pragma unroll
    for (int r = 0; r < 4; ++r) {
      int row = m0 + 16*w + q*4 + r;
      int b = row / LQ, i = row - b*LQ;
      float v = acc[ns][r];
      if (c < 512) {                     // Q: scale only (biases folded in attn)
        int h = c >> 6, d = c & 63;
        Qb[(((size_t)(b*8 + h))*LQ + i)*64 + d] = f2bf(v * 0.125f);
      } else if (c < 1024) {             // K
        int cc = c - 512, h = cc >> 6, d = cc & 63;
        Kc[(((size_t)(b*8 + h))*LQ + i)*64 + d] = f2bf(v);
      } else {                           // V -> transposed (bh, v, j)
        int cc = c - 1024, h = cc / 96, vv = cc - h*96;
        Vt[(((size_t)(b*8 + h))*96 + vv)*LQ + i] = f2bf(v);
      }
    }
  }
}

// ---------------------------------------------------------------------------
// K5: fused attention, flash-style online softmax.
// grid (24 i-tiles, 32 bh) x 256 (4 waves; wave w owns query rows 16w..16w+15)
// content: (Q+rwb) @ K ; rel: (Q+rrb) @ rK band (k0 = j0-i0+L-64); band col
// needed per wave: [48-16w, 126-16w] -> 5 n-subtiles; diagonal shift via LDS.
// ---------------------------------------------------------------------------
__global__ __launch_bounds__(256) void attn_k(
    const u16* __restrict__ Qb, const u16* __restrict__ Kc,
    const u16* __restrict__ Vt, const u16* __restrict__ rK,
    const float* __restrict__ rwb, const float* __restrict__ rrb,
    u16* __restrict__ attnO)
{
  const int it = blockIdx.x, bh = blockIdx.y;
  const int i0 = it * 64;
  const int b = bh >> 3, h = bh & 7;
  const int tid = threadIdx.x;
  const int w = tid >> 6, lane = tid & 63, q = lane >> 4, s = lane & 15;

  __shared__ float Gs[4][16][128];
  __shared__ __align__(16) u16 Ps[4][16][64];

  // Q fragments with biases folded (f32 add, then round)
  Frag qwf[2], qrf[2];
  {
    const u16* qb = Qb + (((size_t)bh)*LQ + i0 + 16*w + s)*64;
    #pragma unroll
    for (int kf = 0; kf < 2; ++kf) {
      u16x8_t qraw = *(const u16x8_t*)(qb + kf*32 + q*8);
      #pragma unroll
      for (int j = 0; j < 8; ++j) {
        int d = kf*32 + q*8 + j;
        float qv = bf2f(qraw[j]);
        qwf[kf].u[j] = f2bf(qv + rwb[h*64 + d]);
        qrf[kf].u[j] = f2bf(qv + rrb[h*64 + d]);
      }
    }
  }

  const f32x4_t fz = {0.f, 0.f, 0.f, 0.f};
  float mrun[4], lrun[4];
  f32x4_t acco[6];
  #pragma unroll
  for (int r = 0; r < 4; ++r) { mrun[r] = -1e30f; lrun[r] = 0.f; }
  #pragma unroll
  for (int vs = 0; vs < 6; ++vs) acco[vs] = fz;

  const u16* kcb = Kc + ((size_t)bh)*LQ*64;
  const u16* vtb = Vt + ((size_t)bh)*96*LQ;
  const u16* rkb = rK + ((size_t)h)*NPOSP*64;

  for (int jt = 0; jt < 24; ++jt) {
    const int j0 = jt * 64;

    // ---- content scores: 16x64 per wave
    f32x4_t accc[4] = {fz, fz, fz, fz};
    #pragma unroll
    for (int kf = 0; kf < 2; ++kf) {
      #pragma unroll
      for (int ns = 0; ns < 4; ++ns) {
        Frag bf; bf.u = *(const u16x8_t*)(kcb + (size_t)(j0 + ns*16 + s)*64 + kf*32 + q*8);
        accc[ns] = __builtin_amdgcn_mfma_f32_16x16x32_bf16(qwf[kf].b, bf.b, accc[ns], 0, 0, 0);
      }
    }

    // ---- rel band scores: 16 x 80 (subtiles 3-w..7-w of 128 band cols)
    const int k0 = j0 - i0 + (LQ - 64);
    f32x4_t accr[5] = {fz, fz, fz, fz, fz};
    #pragma unroll
    for (int kf = 0; kf < 2; ++kf) {
      #pragma unroll
      for (int nn = 0; nn < 5; ++nn) {
        int ns2 = 3 - w + nn;
        Frag bf; bf.u = *(const u16x8_t*)(rkb + (size_t)(k0 + ns2*16 + s)*64 + kf*32 + q*8);
        accr[nn] = __builtin_amdgcn_mfma_f32_16x16x32_bf16(qrf[kf].b, bf.b, accr[nn], 0, 0, 0);
      }
    }

    // ---- stash band tile (C-layout) in per-wave LDS
    #pragma unroll
    for (int nn = 0; nn < 5; ++nn) {
      int ns2 = 3 - w + nn;
      #pragma unroll
      for (int r = 0; r < 4; ++r)
        Gs[w][q*4 + r][ns2*16 + s] = accr[nn][r];
    }
    __syncthreads();

    // ---- combine with diagonal shift + online softmax
    float Sv[4][4];
    #pragma unroll
    for (int ns = 0; ns < 4; ++ns) {
      int n = ns*16 + s;
      #pragma unroll
      for (int r = 0; r < 4; ++r) {
        int il = 16*w + q*4 + r;                       // i - i0
        Sv[ns][r] = accc[ns][r] + Gs[w][q*4 + r][n + 63 - il];
      }
    }
    #pragma unroll
    for (int r = 0; r < 4; ++r) {
      float mx = fmaxf(fmaxf(Sv[0][r], Sv[1][r]), fmaxf(Sv[2][r], Sv[3][r]));
      for (int d = 1; d < 16; d <<= 1) mx = fmaxf(mx, __shfl_xor(mx, d, 64));
      float mnew  = fmaxf(mrun[r], mx);
      float alpha = __expf(mrun[r] - mnew);
      float sum = 0.f;
      #pragma unroll
      for (int ns = 0; ns < 4; ++ns) {
        float p = __expf(Sv[ns][r] - mnew);
        Sv[ns][r] = p; sum += p;
      }
      for (int d = 1; d < 16; d <<= 1) sum += __shfl_xor(sum, d, 64);
      mrun[r] = mnew;
      lrun[r] = lrun[r]*alpha + sum;
      #pragma unroll
      for (int vs = 0; vs < 6; ++vs) acco[vs][r] *= alpha;
    }

    // ---- P: C-layout -> LDS -> A-layout
    #pragma unroll
    for (int ns = 0; ns < 4; ++ns)
      #pragma unroll
      for (int r = 0; r < 4; ++r)
        Ps[w][q*4 + r][ns*16 + s] = f2bf(Sv[ns][r]);
    __syncthreads();

    // ---- PV: P(16x64) @ V(64x96) via Vt rows
    #pragma unroll
    for (int kf = 0; kf < 2; ++kf) {
      Frag pf; pf.u = *(const u16x8_t*)(&Ps[w][s][kf*32 + q*8]);
      #pragma unroll
      for (int vs = 0; vs < 6; ++vs) {
        Frag vf; vf.u = *(const u16x8_t*)(vtb + (size_t)(vs*16 + s)*LQ + j0 + kf*32 + q*8);
        acco[vs] = __builtin_amdgcn_mfma_f32_16x16x32_bf16(pf.b, vf.b, acco[vs], 0, 0, 0);
      }
    }
  }

  // ---- epilogue: normalize and write attnO (b, i, h*96+v)
  #pragma unroll
  for (int vs = 0; vs < 6; ++vs) {
    int v = vs*16 + s;
    #pragma unroll
    for (int r = 0; r < 4; ++r) {
      int i = i0 + 16*w + q*4 + r;
      float o = acco[vs][r] / lrun[r];
      attnO[((size_t)b*LQ + i)*768 + h*96 + v] = f2bf(o);
    }
  }
}

// ---------------------------------------------------------------------------
// K6: output projection (M=6144, N=768, K=768) + bias -> d_out FLOAT
// grid (12, 96) x 256
// ---------------------------------------------------------------------------
__global__ __launch_bounds__(256) void out_gemm(
    const u16* __restrict__ A, const u16* __restrict__ Wt,
    const float* __restrict__ bias, float* __restrict__ out)
{
  const int n0 = blockIdx.x * 64;
  const int m0 = blockIdx.y * 64;
  const int tid = threadIdx.x, w = tid >> 6, lane = tid & 63, q = lane >> 4, s = lane & 15;

  const u16* arow = A  + (size_t)(m0 + 16*w + s) * 768;
  const u16* brow = Wt + (size_t)n0 * 768;

  const f32x4_t fz = {0.f, 0.f, 0.f, 0.f};
  f32x4_t acc[4] = {fz, fz, fz, fz};

  for (int kk = 0; kk < 768; kk += 32) {
    Frag af; af.u = *(const u16x8_t*)(arow + kk + q*8);
    #pragma unroll
    for (int ns = 0; ns < 4; ++ns) {
      Frag bf; bf.u = *(const u16x8_t*)(brow + (size_t)(ns*16 + s)*768 + kk + q*8);
      acc[ns] = __builtin_amdgcn_mfma_f32_16x16x32_bf16(af.b, bf.b, acc[ns], 0, 0, 0);
    }
  }

  #pragma unroll
  for (int ns = 0; ns < 4; ++ns) {
    int c = n0 + ns*16 + s;
    float bv = bias[c];
    #pragma unroll
    for (int r = 0; r < 4; ++r) {
      int row = m0 + 16*w + q*4 + r;
      out[(size_t)row*768 + c] = acc[ns][r] + bv;   // f32 store (output dtype = f32)
    }
  }
}

// ---------------------------------------------------------------------------
extern "C" void kernel_launch(void* const* d_in, const int* in_sizes, int n_in,
                              void* d_out, int out_size, void* d_ws, size_t ws_size,
                              hipStream_t stream)
{
  (void)out_size; (void)ws_size;

  // dict-order binding (verified R5: in_sizes matches dict signature);
  // by-size fallback kept for safety.
  static const int dict_sig[9] = {4718592,393216,393216,589824,589824,768,49152,512,512};
  bool is_dict = (n_in == 9);
  for (int i = 0; i < 9 && i < n_in; ++i)
    if (in_sizes[i] != dict_sig[i]) is_dict = false;

  const float *x, *Qw_w, *Kw_w, *Vw_w, *Ow_w, *out_b, *relKw, *rwb, *rrb;
  if (is_dict) {
    x     = (const float*)d_in[0];  Qw_w  = (const float*)d_in[1];
    Kw_w  = (const float*)d_in[2];  Vw_w  = (const float*)d_in[3];
    Ow_w  = (const float*)d_in[4];  out_b = (const float*)d_in[5];
    relKw = (const float*)d_in[6];  rwb   = (const float*)d_in[7];
    rrb   = (const float*)d_in[8];
  } else {
    const float* p393[2] = {nullptr,nullptr}; int n393 = 0;
    const float* p589[2] = {nullptr,nullptr}; int n589 = 0;
    const float* p512[2] = {nullptr,nullptr}; int n512 = 0;
    const float *px = nullptr, *prel = nullptr, *pb = nullptr;
    for (int i = 0; i < n_in; ++i) {
      const float* p = (const float*)d_in[i];
      switch (in_sizes[i]) {
        case 4718592: px = p; break;
        case 49152:   prel = p; break;
        case 768:     pb = p; break;
        case 393216:  if (n393 < 2) p393[n393++] = p; break;
        case 589824:  if (n589 < 2) p589[n589++] = p; break;
        case 512:     if (n512 < 2) p512[n512++] = p; break;
        default: break;
      }
    }
    x = px; relKw = prel; out_b = pb;
    Qw_w = p393[0]; Kw_w = p393[1];
    Vw_w = p589[0]; Ow_w = p589[1];
    rwb  = p512[0]; rrb  = p512[1];
  }

  float* out = (float*)d_out;

  char* ws = (char*)d_ws;
  size_t off = 0;
  auto alloc = [&](size_t bytes) -> void* {
    void* p = ws + off;
    off += (bytes + 255) & ~(size_t)255;
    return p;
  };

  float* gmax  = (float*)alloc(256);
  u16*   WtQKV = (u16*)  alloc((size_t)1792*768*2);   // 2.75 MB
  u16*   WtOut = (u16*)  alloc((size_t)768*768*2);    // 1.18 MB
  u16*   rK    = (u16*)  alloc((size_t)8*NPOSP*64*2); // 3 MB
  u16*   Qb    = (u16*)  alloc((size_t)32*LQ*64*2);   // 6.3 MB
  u16*   Kc    = (u16*)  alloc((size_t)32*LQ*64*2);   // 6.3 MB
  u16*   Vt    = (u16*)  alloc((size_t)32*96*LQ*2);   // 9.4 MB
  u16*   xb    = (u16*)  alloc((size_t)6144*768*2);   // 9.4 MB (~38 MB total)
  u16*   attnO = xb;  // alias: xb dead after qkv_gemm

  cvt_x      <<<dim3(4608), dim3(256), 0, stream>>>(x, xb);
  transpose_w<<<dim3(2560), dim3(256), 0, stream>>>(Qw_w, Kw_w, Vw_w, Ow_w, WtQKV, WtOut);
  gamma_max_k<<<dim3(16),   dim3(256), 0, stream>>>(gmax);
  rk_k       <<<dim3(NPOSP),dim3(256), 0, stream>>>(gmax, relKw, rK);
  qkv_gemm   <<<dim3(28,96),dim3(256), 0, stream>>>(xb, WtQKV, Qb, Kc, Vt);
  attn_k     <<<dim3(24,32),dim3(256), 0, stream>>>(Qb, Kc, Vt, rK, rwb, rrb, attnO);
  out_gemm   <<<dim3(12,96),dim3(256), 0, stream>>>(attnO, WtOut, out_b, out);
}

// Round 7
// 601.853 us; speedup vs baseline: 1.0023x; 1.0023x over previous
//
#include <hip/hip_runtime.h>

// ---------------------------------------------------------------------------
// MHSelfAttention (Transformer-XL relative shift), MI355X gfx950
// B=4 L=1536 D=768 H=8 DQK=64 DV=96 NPF=96
// logits[b,h,i,j] = (Q*s+rwb)[i].K[j] + (Q*s+rrb)[i].rK[j-i+L-1]
// R7: attn_k restructured — barrier-free (per-wave LDS only), Gs LDS round-
// trip replaced by ds_bpermute diagonal shift, j-loop split 2-way (flash
// combine) to lift occupancy 12 -> 24 waves/CU. Inputs f32 dict order; out f32.
// ---------------------------------------------------------------------------

typedef unsigned short u16;
typedef unsigned int   u32;

typedef __bf16 bf16x8_t __attribute__((ext_vector_type(8)));
typedef unsigned short u16x8_t __attribute__((ext_vector_type(8)));
typedef float f32x4_t __attribute__((ext_vector_type(4)));

union Frag { u16x8_t u; bf16x8_t b; };

__device__ __forceinline__ float bf2f(u16 v){
  union { u32 i; float f; } c; c.i = ((u32)v) << 16; return c.f;
}
__device__ __forceinline__ u16 f2bf(float f){
  union { float f; u32 i; } c; c.f = f;
  u32 r = c.i + 0x7FFFu + ((c.i >> 16) & 1u);
  return (u16)(r >> 16);
}

#define LQ   1536
#define NPOS 3071   // 2L-1
#define NPOSP 3072  // row stride (row 3071 zeroed; indices j-i+1535 <= 3070)

// ---------------------------------------------------------------------------
// K0a: x (f32) -> bf16 staging. grid 4608 x 256, 4 elems/thread
// ---------------------------------------------------------------------------
__global__ void cvt_x(const float* __restrict__ x, u16* __restrict__ xb)
{
  int gid = blockIdx.x * 256 + threadIdx.x;
  float4 v = ((const float4*)x)[gid];
  xb[4*gid+0] = f2bf(v.x); xb[4*gid+1] = f2bf(v.y);
  xb[4*gid+2] = f2bf(v.z); xb[4*gid+3] = f2bf(v.w);
}

// ---------------------------------------------------------------------------
// K0b: weight transposes -> K-major (N x K) bf16 for MFMA B-fragment loads
// grid 2560 x 256. cols 0..1791 -> WtQKV (Q|K|V), 1792.. -> WtOut
// ---------------------------------------------------------------------------
__global__ void transpose_w(const float* __restrict__ Qw_, const float* __restrict__ Kw_,
                            const float* __restrict__ Vw_, const float* __restrict__ Ow_,
                            u16* __restrict__ WtQKV, u16* __restrict__ WtOut)
{
  int c = blockIdx.x;
  if (c < 1792) {
    const float* src; int cl, stride;
    if (c < 512)       { src = Qw_; cl = c;        stride = 512; }
    else if (c < 1024) { src = Kw_; cl = c - 512;  stride = 512; }
    else               { src = Vw_; cl = c - 1024; stride = 768; }
    for (int k = threadIdx.x; k < 768; k += 256)
      WtQKV[(size_t)c*768 + k] = f2bf(src[(size_t)k*stride + cl]);
  } else {
    int c2 = c - 1792;
    for (int k = threadIdx.x; k < 768; k += 256)
      WtOut[(size_t)c2*768 + k] = f2bf(Ow_[(size_t)k*768 + c2]);
  }
}

// ---------------------------------------------------------------------------
// K1: per-gamma-feature max over |pos| in [0,1535]   (16 blocks x 256)
// ---------------------------------------------------------------------------
__global__ void gamma_max_k(float* __restrict__ gmax)
{
  int f = blockIdx.x;                 // 0..15
  float fi   = (float)(f + 1);
  float conc = 4.0f * fi * fi;
  float rate = fi / 24.0f;
  float c1   = conc - 1.0f;
  float lognorm = lgammaf(conc) - conc * logf(rate);
  float mx = 0.0f;
  for (int x = threadIdx.x; x < 1536; x += 256) {
    float xf = (float)x;
    float lu = (x == 0) ? -INFINITY : (c1 * logf(xf) - rate * xf);
    float p  = expf(lu - lognorm) + 1e-8f;
    mx = fmaxf(mx, p);
  }
  for (int d = 1; d < 64; d <<= 1) mx = fmaxf(mx, __shfl_xor(mx, d, 64));
  __shared__ float red[4];
  if ((threadIdx.x & 63) == 0) red[threadIdx.x >> 6] = mx;
  __syncthreads();
  if (threadIdx.x == 0)
    gmax[f] = fmaxf(fmaxf(red[0], red[1]), fmaxf(red[2], red[3]));
}

// ---------------------------------------------------------------------------
// K2: rK[h][k][d] = sum_f pe_feats(k)[f] * relKw[f][h*64+d], bf16 (8,3072,64)
// ---------------------------------------------------------------------------
__global__ void rk_k(const float* __restrict__ gmax,
                     const float* __restrict__ relKw, u16* __restrict__ rK)
{
  int k = blockIdx.x;
  int t = threadIdx.x;
  if (k == NPOS) {
    for (int c = t; c < 512; c += 256)
      rK[(((size_t)(c >> 6))*NPOSP + NPOS)*64 + (c & 63)] = 0;
    return;
  }
  __shared__ float feats[96];
  float pos = (float)(k - (LQ - 1));
  float x   = fabsf(pos);
  float sgn = (float)((pos > 0.0f) - (pos < 0.0f));
  if (t < 96) {
    int tb = (t < 48) ? t : t - 48;
    float val;
    if (tb < 16) {
      float max_range = log2f((float)LQ);
      float hl = exp2f(3.0f + (float)tb * (max_range - 3.0f) / 15.0f);
      val = expf(-0.69314718056f / hl * x);
    } else if (tb < 32) {
      int i = tb - 16;
      float width = (float)(1u << (i + 1)) - 1.0f;
      val = (width > x) ? 1.0f : 0.0f;
    } else {
      int i = tb - 32;
      float fi   = (float)(i + 1);
      float conc = 4.0f * fi * fi;
      float rate = fi / 24.0f;
      float lognorm = lgammaf(conc) - conc * logf(rate);
      float lu = (x == 0.0f) ? -INFINITY : ((conc - 1.0f) * logf(x) - rate * x);
      float p  = expf(lu - lognorm) + 1e-8f;
      val = p / gmax[i];
    }
    feats[t] = (t < 48) ? val : sgn * val;
  }
  __syncthreads();
  for (int c = t; c < 512; c += 256) {
    float acc = 0.0f;
    #pragma unroll 8
    for (int f = 0; f < 96; ++f) acc += feats[f] * relKw[(size_t)f*512 + c];
    rK[(((size_t)(c >> 6))*NPOSP + k)*64 + (c & 63)] = f2bf(acc);
  }
}

// ---------------------------------------------------------------------------
// K4: fused QKV projection GEMM (M=6144, N=1792, K=768), MFMA 16x16x32 bf16
// ---------------------------------------------------------------------------
__global__ __launch_bounds__(256) void qkv_gemm(
    const u16* __restrict__ xb, const u16* __restrict__ Wt,
    u16* __restrict__ Qb, u16* __restrict__ Kc, u16* __restrict__ Vt)
{
  const int n0 = blockIdx.x * 64;
  const int m0 = blockIdx.y * 64;
  const int tid = threadIdx.x, w = tid >> 6, lane = tid & 63, q = lane >> 4, s = lane & 15;

  const u16* arow = xb + (size_t)(m0 + 16*w + s) * 768;
  const u16* brow = Wt + (size_t)n0 * 768;

  const f32x4_t fz = {0.f, 0.f, 0.f, 0.f};
  f32x4_t acc[4] = {fz, fz, fz, fz};

  for (int kk = 0; kk < 768; kk += 32) {
    Frag af; af.u = *(const u16x8_t*)(arow + kk + q*8);
    #pragma unroll
    for (int ns = 0; ns < 4; ++ns) {
      Frag bf; bf.u = *(const u16x8_t*)(brow + (size_t)(ns*16 + s)*768 + kk + q*8);
      acc[ns] = __builtin_amdgcn_mfma_f32_16x16x32_bf16(af.b, bf.b, acc[ns], 0, 0, 0);
    }
  }

  #pragma unroll
  for (int ns = 0; ns < 4; ++ns) {
    int c = n0 + ns*16 + s;
    #pragma unroll
    for (int r = 0; r < 4; ++r) {
      int row = m0 + 16*w + q*4 + r;
      int b = row / LQ, i = row - b*LQ;
      float v = acc[ns][r];
      if (c < 512) {
        int h = c >> 6, d = c & 63;
        Qb[(((size_t)(b*8 + h))*LQ + i)*64 + d] = f2bf(v * 0.125f);
      } else if (c < 1024) {
        int cc = c - 512, h = cc >> 6, d = cc & 63;
        Kc[(((size_t)(b*8 + h))*LQ + i)*64 + d] = f2bf(v);
      } else {
        int cc = c - 1024, h = cc / 96, vv = cc - h*96;
        Vt[(((size_t)(b*8 + h))*96 + vv)*LQ + i] = f2bf(v);
      }
    }
  }
}

// ---------------------------------------------------------------------------
// K5: fused attention, flash-style online softmax. BARRIER-FREE.
// grid (24 i-tiles, 32 bh, nz) x 256; wave w owns query rows 16w..16w+15 and
// touches only its own LDS slice -> no __syncthreads anywhere.
// Diagonal shift done with ds_bpermute: for dest (ns,r) at lane (q,s):
//   tt = s+15-4q-r; src lane = (lane&48)|(tt&15); reg = accr[ns+(tt>=16)][r]
// (algebraically identical to the old Gs LDS round-trip; 16w terms cancel).
// nz==1: write normalized attnO. nz==2: write unnormalized partials + (m,l).
// ---------------------------------------------------------------------------
__global__ __launch_bounds__(256) void attn_k(
    const u16* __restrict__ Qb, const u16* __restrict__ Kc,
    const u16* __restrict__ Vt, const u16* __restrict__ rK,
    const float* __restrict__ rwb, const float* __restrict__ rrb,
    u16* __restrict__ attnO, u16* __restrict__ Opart, float* __restrict__ ml,
    int nz)
{
  const int it = blockIdx.x, bh = blockIdx.y, z = blockIdx.z;
  const int i0 = it * 64;
  const int b = bh >> 3, h = bh & 7;
  const int tid = threadIdx.x;
  const int w = tid >> 6, lane = tid & 63, q = lane >> 4, s = lane & 15;

  __shared__ __align__(16) u16 Ps[4][16][72];   // stride 72 to spread banks

  // Q fragments with biases folded (f32 add, then round)
  Frag qwf[2], qrf[2];
  {
    const u16* qb = Qb + (((size_t)bh)*LQ + i0 + 16*w + s)*64;
    #pragma unroll
    for (int kf = 0; kf < 2; ++kf) {
      u16x8_t qraw = *(const u16x8_t*)(qb + kf*32 + q*8);
      #pragma unroll
      for (int j = 0; j < 8; ++j) {
        int d = kf*32 + q*8 + j;
        float qv = bf2f(qraw[j]);
        qwf[kf].u[j] = f2bf(qv + rwb[h*64 + d]);
        qrf[kf].u[j] = f2bf(qv + rrb[h*64 + d]);
      }
    }
  }

  const f32x4_t fz = {0.f, 0.f, 0.f, 0.f};
  float mrun[4], lrun[4];
  f32x4_t acco[6];
  #pragma unroll
  for (int r = 0; r < 4; ++r) { mrun[r] = -1e30f; lrun[r] = 0.f; }
  #pragma unroll
  for (int vs = 0; vs < 6; ++vs) acco[vs] = fz;

  const u16* kcb = Kc + ((size_t)bh)*LQ*64;
  const u16* vtb = Vt + ((size_t)bh)*96*LQ;
  const u16* rkb = rK + ((size_t)h)*NPOSP*64;

  const int njt = 24 / nz;
  const int jt0 = z * njt;

  for (int jt = jt0; jt < jt0 + njt; ++jt) {
    const int j0 = jt * 64;

    // ---- content scores: 16x64 per wave
    f32x4_t accc[4] = {fz, fz, fz, fz};
    #pragma unroll
    for (int kf = 0; kf < 2; ++kf) {
      #pragma unroll
      for (int ns = 0; ns < 4; ++ns) {
        Frag bf; bf.u = *(const u16x8_t*)(kcb + (size_t)(j0 + ns*16 + s)*64 + kf*32 + q*8);
        accc[ns] = __builtin_amdgcn_mfma_f32_16x16x32_bf16(qwf[kf].b, bf.b, accc[ns], 0, 0, 0);
      }
    }

    // ---- rel band scores: 16 x 80 (subtiles 3-w..7-w of 128 band cols)
    const int k0 = j0 - i0 + (LQ - 64);
    f32x4_t accr[5] = {fz, fz, fz, fz, fz};
    #pragma unroll
    for (int kf = 0; kf < 2; ++kf) {
      #pragma unroll
      for (int nn = 0; nn < 5; ++nn) {
        int ns2 = 3 - w + nn;
        Frag bf; bf.u = *(const u16x8_t*)(rkb + (size_t)(k0 + ns2*16 + s)*64 + kf*32 + q*8);
        accr[nn] = __builtin_amdgcn_mfma_f32_16x16x32_bf16(qrf[kf].b, bf.b, accr[nn], 0, 0, 0);
      }
    }

    // ---- diagonal shift via bpermute (replaces Gs LDS round-trip)
    #pragma unroll
    for (int r = 0; r < 4; ++r) {
      int tt = s + 15 - 4*q - r;               // in [0, 30]
      int srcl = (lane & 48) | (tt & 15);
      bool hi = tt >= 16;
      #pragma unroll
      for (int ns = 0; ns < 4; ++ns) {
        float v0 = __shfl(accr[ns][r],     srcl, 64);
        float v1 = __shfl(accr[ns + 1][r], srcl, 64);
        accc[ns][r] += hi ? v1 : v0;
      }
    }

    // ---- online softmax (in place on accc)
    #pragma unroll
    for (int r = 0; r < 4; ++r) {
      float mx = fmaxf(fmaxf(accc[0][r], accc[1][r]), fmaxf(accc[2][r], accc[3][r]));
      for (int d = 1; d < 16; d <<= 1) mx = fmaxf(mx, __shfl_xor(mx, d, 64));
      float mnew  = fmaxf(mrun[r], mx);
      float alpha = __expf(mrun[r] - mnew);
      float sum = 0.f;
      #pragma unroll
      for (int ns = 0; ns < 4; ++ns) {
        float p = __expf(accc[ns][r] - mnew);
        accc[ns][r] = p; sum += p;
      }
      for (int d = 1; d < 16; d <<= 1) sum += __shfl_xor(sum, d, 64);
      mrun[r] = mnew;
      lrun[r] = lrun[r]*alpha + sum;
      #pragma unroll
      for (int vs = 0; vs < 6; ++vs) acco[vs][r] *= alpha;
    }

    // ---- P: C-layout -> per-wave LDS -> A-layout (no barrier: same wave)
    #pragma unroll
    for (int ns = 0; ns < 4; ++ns)
      #pragma unroll
      for (int r = 0; r < 4; ++r)
        Ps[w][q*4 + r][ns*16 + s] = f2bf(accc[ns][r]);

    // ---- PV: P(16x64) @ V(64x96) via Vt rows
    #pragma unroll
    for (int kf = 0; kf < 2; ++kf) {
      Frag pf; pf.u = *(const u16x8_t*)(&Ps[w][s][kf*32 + q*8]);
      #pragma unroll
      for (int vs = 0; vs < 6; ++vs) {
        Frag vf; vf.u = *(const u16x8_t*)(vtb + (size_t)(vs*16 + s)*LQ + j0 + kf*32 + q*8);
        acco[vs] = __builtin_amdgcn_mfma_f32_16x16x32_bf16(pf.b, vf.b, acco[vs], 0, 0, 0);
      }
    }
  }

  // ---- epilogue
  if (nz == 1) {
    #pragma unroll
    for (int vs = 0; vs < 6; ++vs) {
      int v = vs*16 + s;
      #pragma unroll
      for (int r = 0; r < 4; ++r) {
        int i = i0 + 16*w + q*4 + r;
        attnO[((size_t)b*LQ + i)*768 + h*96 + v] = f2bf(acco[vs][r] / lrun[r]);
      }
    }
  } else {
    #pragma unroll
    for (int vs = 0; vs < 6; ++vs) {
      int v = vs*16 + s;
      #pragma unroll
      for (int r = 0; r < 4; ++r) {
        int i = i0 + 16*w + q*4 + r;
        size_t rg = (size_t)(z*32 + bh)*LQ + i;
        Opart[rg*96 + v] = f2bf(acco[vs][r]);
      }
    }
    if (s == 0) {
      #pragma unroll
      for (int r = 0; r < 4; ++r) {
        int i = i0 + 16*w + q*4 + r;
        size_t rg = (size_t)(z*32 + bh)*LQ + i;
        ml[rg*2 + 0] = mrun[r];
        ml[rg*2 + 1] = lrun[r];
      }
    }
  }
}

// ---------------------------------------------------------------------------
// K5b: flash combine of nz j-partials -> attnO bf16. grid 18432 x 256.
// ---------------------------------------------------------------------------
__global__ void combine_k(const u16* __restrict__ Opart, const float* __restrict__ ml,
                          u16* __restrict__ attnO, int nz)
{
  int g = blockIdx.x * 256 + threadIdx.x;
  if (g >= 32*LQ*96) return;
  int v = g % 96, row = g / 96;
  int bh = row / LQ, i = row - bh*LQ;
  int b = bh >> 3, h = bh & 7;
  float M = -1e30f;
  for (int z = 0; z < nz; ++z)
    M = fmaxf(M, ml[((size_t)(z*32 + bh)*LQ + i)*2]);
  float L = 0.f, num = 0.f;
  for (int z = 0; z < nz; ++z) {
    size_t rg = (size_t)(z*32 + bh)*LQ + i;
    float e = __expf(ml[rg*2] - M);
    L   += ml[rg*2 + 1] * e;
    num += bf2f(Opart[rg*96 + v]) * e;
  }
  attnO[((size_t)b*LQ + i)*768 + h*96 + v] = f2bf(num / L);
}

// ---------------------------------------------------------------------------
// K6: output projection (M=6144, N=768, K=768) + bias -> d_out FLOAT
// ---------------------------------------------------------------------------
__global__ __launch_bounds__(256) void out_gemm(
    const u16* __restrict__ A, const u16* __restrict__ Wt,
    const float* __restrict__ bias, float* __restrict__ out)
{
  const int n0 = blockIdx.x * 64;
  const int m0 = blockIdx.y * 64;
  const int tid = threadIdx.x, w = tid >> 6, lane = tid & 63, q = lane >> 4, s = lane & 15;

  const u16* arow = A  + (size_t)(m0 + 16*w + s) * 768;
  const u16* brow = Wt + (size_t)n0 * 768;

  const f32x4_t fz = {0.f, 0.f, 0.f, 0.f};
  f32x4_t acc[4] = {fz, fz, fz, fz};

  for (int kk = 0; kk < 768; kk += 32) {
    Frag af; af.u = *(const u16x8_t*)(arow + kk + q*8);
    #pragma unroll
    for (int ns = 0; ns < 4; ++ns) {
      Frag bf; bf.u = *(const u16x8_t*)(brow + (size_t)(ns*16 + s)*768 + kk + q*8);
      acc[ns] = __builtin_amdgcn_mfma_f32_16x16x32_bf16(af.b, bf.b, acc[ns], 0, 0, 0);
    }
  }

  #pragma unroll
  for (int ns = 0; ns < 4; ++ns) {
    int c = n0 + ns*16 + s;
    float bv = bias[c];
    #pragma unroll
    for (int r = 0; r < 4; ++r) {
      int row = m0 + 16*w + q*4 + r;
      out[(size_t)row*768 + c] = acc[ns][r] + bv;
    }
  }
}

// ---------------------------------------------------------------------------
extern "C" void kernel_launch(void* const* d_in, const int* in_sizes, int n_in,
                              void* d_out, int out_size, void* d_ws, size_t ws_size,
                              hipStream_t stream)
{
  (void)out_size;

  static const int dict_sig[9] = {4718592,393216,393216,589824,589824,768,49152,512,512};
  bool is_dict = (n_in == 9);
  for (int i = 0; i < 9 && i < n_in; ++i)
    if (in_sizes[i] != dict_sig[i]) is_dict = false;

  const float *x, *Qw_w, *Kw_w, *Vw_w, *Ow_w, *out_b, *relKw, *rwb, *rrb;
  if (is_dict) {
    x     = (const float*)d_in[0];  Qw_w  = (const float*)d_in[1];
    Kw_w  = (const float*)d_in[2];  Vw_w  = (const float*)d_in[3];
    Ow_w  = (const float*)d_in[4];  out_b = (const float*)d_in[5];
    relKw = (const float*)d_in[6];  rwb   = (const float*)d_in[7];
    rrb   = (const float*)d_in[8];
  } else {
    const float* p393[2] = {nullptr,nullptr}; int n393 = 0;
    const float* p589[2] = {nullptr,nullptr}; int n589 = 0;
    const float* p512[2] = {nullptr,nullptr}; int n512 = 0;
    const float *px = nullptr, *prel = nullptr, *pb = nullptr;
    for (int i = 0; i < n_in; ++i) {
      const float* p = (const float*)d_in[i];
      switch (in_sizes[i]) {
        case 4718592: px = p; break;
        case 49152:   prel = p; break;
        case 768:     pb = p; break;
        case 393216:  if (n393 < 2) p393[n393++] = p; break;
        case 589824:  if (n589 < 2) p589[n589++] = p; break;
        case 512:     if (n512 < 2) p512[n512++] = p; break;
        default: break;
      }
    }
    x = px; relKw = prel; out_b = pb;
    Qw_w = p393[0]; Kw_w = p393[1];
    Vw_w = p589[0]; Ow_w = p589[1];
    rwb  = p512[0]; rrb  = p512[1];
  }

  float* out = (float*)d_out;

  char* ws = (char*)d_ws;
  size_t off = 0;
  auto alloc = [&](size_t bytes) -> void* {
    void* p = ws + off;
    off += (bytes + 255) & ~(size_t)255;
    return p;
  };

  float* gmax  = (float*)alloc(256);
  u16*   WtQKV = (u16*)  alloc((size_t)1792*768*2);   // 2.75 MB
  u16*   WtOut = (u16*)  alloc((size_t)768*768*2);    // 1.18 MB
  u16*   rK    = (u16*)  alloc((size_t)8*NPOSP*64*2); // 3 MB
  u16*   Qb    = (u16*)  alloc((size_t)32*LQ*64*2);   // 6.3 MB
  u16*   Kc    = (u16*)  alloc((size_t)32*LQ*64*2);   // 6.3 MB
  u16*   Vt    = (u16*)  alloc((size_t)32*96*LQ*2);   // 9.4 MB
  u16*   xb    = (u16*)  alloc((size_t)6144*768*2);   // 9.4 MB
  u16*   attnO = xb;  // alias: xb dead after qkv_gemm
  // j-split partials (nz=2): 18.9 MB + 0.8 MB -> total ~58 MB
  size_t off_before_part = off;
  u16*   Opart = (u16*)  alloc((size_t)2*32*LQ*96*2);
  float* ml    = (float*)alloc((size_t)2*32*LQ*2*4);
  int nz = (ws_size >= off) ? 2 : 1;
  if (nz == 1) off = off_before_part;   // partials unused

  cvt_x      <<<dim3(4608), dim3(256), 0, stream>>>(x, xb);
  transpose_w<<<dim3(2560), dim3(256), 0, stream>>>(Qw_w, Kw_w, Vw_w, Ow_w, WtQKV, WtOut);
  gamma_max_k<<<dim3(16),   dim3(256), 0, stream>>>(gmax);
  rk_k       <<<dim3(NPOSP),dim3(256), 0, stream>>>(gmax, relKw, rK);
  qkv_gemm   <<<dim3(28,96),dim3(256), 0, stream>>>(xb, WtQKV, Qb, Kc, Vt);
  attn_k     <<<dim3(24,32,nz),dim3(256), 0, stream>>>(Qb, Kc, Vt, rK, rwb, rrb,
                                                       attnO, Opart, ml, nz);
  if (nz == 2)
    combine_k<<<dim3(18432), dim3(256), 0, stream>>>(Opart, ml, attnO, nz);
  out_gemm   <<<dim3(12,96),dim3(256), 0, stream>>>(attnO, WtOut, out_b, out);
}

// Round 8
// 535.865 us; speedup vs baseline: 1.1257x; 1.1231x over previous
//
#include <hip/hip_runtime.h>

// ---------------------------------------------------------------------------
// MHSelfAttention (Transformer-XL relative shift), MI355X gfx950
// B=4 L=1536 D=768 H=8 DQK=64 DV=96 NPF=96
// logits[b,h,i,j] = (Q*s+rwb)[i].K[j] + (Q*s+rrb)[i].rK[j-i+L-1]
// R8: attn_k rebuilt m97-style — global_load_lds bulk staging of K/rK/V tiles
// (XOR-swizzled chunks for conflict-free ds_read_b128), shared across the 4
// waves; XCD-locality block swizzle (each XCD owns 4 bh). Inputs f32; out f32.
// ---------------------------------------------------------------------------

typedef unsigned short u16;
typedef unsigned int   u32;

typedef __bf16 bf16x8_t __attribute__((ext_vector_type(8)));
typedef unsigned short u16x8_t __attribute__((ext_vector_type(8)));
typedef float f32x4_t __attribute__((ext_vector_type(4)));

union Frag { u16x8_t u; bf16x8_t b; };

__device__ __forceinline__ float bf2f(u16 v){
  union { u32 i; float f; } c; c.i = ((u32)v) << 16; return c.f;
}
__device__ __forceinline__ u16 f2bf(float f){
  union { float f; u32 i; } c; c.f = f;
  u32 r = c.i + 0x7FFFu + ((c.i >> 16) & 1u);
  return (u16)(r >> 16);
}

#define GLB __attribute__((address_space(1)))
#define LDS __attribute__((address_space(3)))
__device__ __forceinline__ void async16(const void* g, void* l){
  __builtin_amdgcn_global_load_lds((const GLB u32*)g, (LDS u32*)l, 16, 0, 0);
}

#define LQ   1536
#define NPOS 3071   // 2L-1
#define NPOSP 3072  // row stride (row 3071 zeroed; indices j-i+1535 <= 3070)

// ---------------------------------------------------------------------------
// K0a: x (f32) -> bf16 staging. grid 4608 x 256, 4 elems/thread
// ---------------------------------------------------------------------------
__global__ void cvt_x(const float* __restrict__ x, u16* __restrict__ xb)
{
  int gid = blockIdx.x * 256 + threadIdx.x;
  float4 v = ((const float4*)x)[gid];
  xb[4*gid+0] = f2bf(v.x); xb[4*gid+1] = f2bf(v.y);
  xb[4*gid+2] = f2bf(v.z); xb[4*gid+3] = f2bf(v.w);
}

// ---------------------------------------------------------------------------
// K0b: weight transposes -> K-major (N x K) bf16 for MFMA B-fragment loads
// ---------------------------------------------------------------------------
__global__ void transpose_w(const float* __restrict__ Qw_, const float* __restrict__ Kw_,
                            const float* __restrict__ Vw_, const float* __restrict__ Ow_,
                            u16* __restrict__ WtQKV, u16* __restrict__ WtOut)
{
  int c = blockIdx.x;
  if (c < 1792) {
    const float* src; int cl, stride;
    if (c < 512)       { src = Qw_; cl = c;        stride = 512; }
    else if (c < 1024) { src = Kw_; cl = c - 512;  stride = 512; }
    else               { src = Vw_; cl = c - 1024; stride = 768; }
    for (int k = threadIdx.x; k < 768; k += 256)
      WtQKV[(size_t)c*768 + k] = f2bf(src[(size_t)k*stride + cl]);
  } else {
    int c2 = c - 1792;
    for (int k = threadIdx.x; k < 768; k += 256)
      WtOut[(size_t)c2*768 + k] = f2bf(Ow_[(size_t)k*768 + c2]);
  }
}

// ---------------------------------------------------------------------------
// K1: per-gamma-feature max over |pos| in [0,1535]   (16 blocks x 256)
// ---------------------------------------------------------------------------
__global__ void gamma_max_k(float* __restrict__ gmax)
{
  int f = blockIdx.x;
  float fi   = (float)(f + 1);
  float conc = 4.0f * fi * fi;
  float rate = fi / 24.0f;
  float c1   = conc - 1.0f;
  float lognorm = lgammaf(conc) - conc * logf(rate);
  float mx = 0.0f;
  for (int x = threadIdx.x; x < 1536; x += 256) {
    float xf = (float)x;
    float lu = (x == 0) ? -INFINITY : (c1 * logf(xf) - rate * xf);
    float p  = expf(lu - lognorm) + 1e-8f;
    mx = fmaxf(mx, p);
  }
  for (int d = 1; d < 64; d <<= 1) mx = fmaxf(mx, __shfl_xor(mx, d, 64));
  __shared__ float red[4];
  if ((threadIdx.x & 63) == 0) red[threadIdx.x >> 6] = mx;
  __syncthreads();
  if (threadIdx.x == 0)
    gmax[f] = fmaxf(fmaxf(red[0], red[1]), fmaxf(red[2], red[3]));
}

// ---------------------------------------------------------------------------
// K2: rK[h][k][d] = sum_f pe_feats(k)[f] * relKw[f][h*64+d], bf16 (8,3072,64)
// ---------------------------------------------------------------------------
__global__ void rk_k(const float* __restrict__ gmax,
                     const float* __restrict__ relKw, u16* __restrict__ rK)
{
  int k = blockIdx.x;
  int t = threadIdx.x;
  if (k == NPOS) {
    for (int c = t; c < 512; c += 256)
      rK[(((size_t)(c >> 6))*NPOSP + NPOS)*64 + (c & 63)] = 0;
    return;
  }
  __shared__ float feats[96];
  float pos = (float)(k - (LQ - 1));
  float x   = fabsf(pos);
  float sgn = (float)((pos > 0.0f) - (pos < 0.0f));
  if (t < 96) {
    int tb = (t < 48) ? t : t - 48;
    float val;
    if (tb < 16) {
      float max_range = log2f((float)LQ);
      float hl = exp2f(3.0f + (float)tb * (max_range - 3.0f) / 15.0f);
      val = expf(-0.69314718056f / hl * x);
    } else if (tb < 32) {
      int i = tb - 16;
      float width = (float)(1u << (i + 1)) - 1.0f;
      val = (width > x) ? 1.0f : 0.0f;
    } else {
      int i = tb - 32;
      float fi   = (float)(i + 1);
      float conc = 4.0f * fi * fi;
      float rate = fi / 24.0f;
      float lognorm = lgammaf(conc) - conc * logf(rate);
      float lu = (x == 0.0f) ? -INFINITY : ((conc - 1.0f) * logf(x) - rate * x);
      float p  = expf(lu - lognorm) + 1e-8f;
      val = p / gmax[i];
    }
    feats[t] = (t < 48) ? val : sgn * val;
  }
  __syncthreads();
  for (int c = t; c < 512; c += 256) {
    float acc = 0.0f;
    #pragma unroll 8
    for (int f = 0; f < 96; ++f) acc += feats[f] * relKw[(size_t)f*512 + c];
    rK[(((size_t)(c >> 6))*NPOSP + k)*64 + (c & 63)] = f2bf(acc);
  }
}

// ---------------------------------------------------------------------------
// K4: fused QKV projection GEMM (M=6144, N=1792, K=768), MFMA 16x16x32 bf16
// ---------------------------------------------------------------------------
__global__ __launch_bounds__(256) void qkv_gemm(
    const u16* __restrict__ xb, const u16* __restrict__ Wt,
    u16* __restrict__ Qb, u16* __restrict__ Kc, u16* __restrict__ Vt)
{
  const int n0 = blockIdx.x * 64;
  const int m0 = blockIdx.y * 64;
  const int tid = threadIdx.x, w = tid >> 6, lane = tid & 63, q = lane >> 4, s = lane & 15;

  const u16* arow = xb + (size_t)(m0 + 16*w + s) * 768;
  const u16* brow = Wt + (size_t)n0 * 768;

  const f32x4_t fz = {0.f, 0.f, 0.f, 0.f};
  f32x4_t acc[4] = {fz, fz, fz, fz};

  for (int kk = 0; kk < 768; kk += 32) {
    Frag af; af.u = *(const u16x8_t*)(arow + kk + q*8);
    #pragma unroll
    for (int ns = 0; ns < 4; ++ns) {
      Frag bf; bf.u = *(const u16x8_t*)(brow + (size_t)(ns*16 + s)*768 + kk + q*8);
      acc[ns] = __builtin_amdgcn_mfma_f32_16x16x32_bf16(af.b, bf.b, acc[ns], 0, 0, 0);
    }
  }

  #pragma unroll
  for (int ns = 0; ns < 4; ++ns) {
    int c = n0 + ns*16 + s;
    #pragma unroll
    for (int r = 0; r < 4; ++r) {
      int row = m0 + 16*w + q*4 + r;
      int b = row / LQ, i = row - b*LQ;
      float v = acc[ns][r];
      if (c < 512) {
        int h = c >> 6, d = c & 63;
        Qb[(((size_t)(b*8 + h))*LQ + i)*64 + d] = f2bf(v * 0.125f);
      } else if (c < 1024) {
        int cc = c - 512, h = cc >> 6, d = cc & 63;
        Kc[(((size_t)(b*8 + h))*LQ + i)*64 + d] = f2bf(v);
      } else {
        int cc = c - 1024, h = cc / 96, vv = cc - h*96;
        Vt[(((size_t)(b*8 + h))*96 + vv)*LQ + i] = f2bf(v);
      }
    }
  }
}

// ---------------------------------------------------------------------------
// K5: fused attention with LDS-staged tiles (m97 pattern).
// 1D grid 768*nz, XCD swizzle: bh = (n&7)*4 + slot/(24*nz) so each XCD owns
// 4 bh values (K/V/rK slices resident in its L2).
// Per jt: stage K(64x64), rK band(128x64), V(96x64) via global_load_lds w=16,
// chunks XOR-swizzled (col16 ^ row&7) so ds_read_b128 frags are conflict-free.
// Diagonal shift via 5 bpermutes/row; online softmax; PV from LDS V.
// ---------------------------------------------------------------------------
__global__ __launch_bounds__(256) void attn_k(
    const u16* __restrict__ Qb, const u16* __restrict__ Kc,
    const u16* __restrict__ Vt, const u16* __restrict__ rK,
    const float* __restrict__ rwb, const float* __restrict__ rrb,
    u16* __restrict__ attnO, u16* __restrict__ Opart, float* __restrict__ ml,
    int nz)
{
  const int n = blockIdx.x;
  const int bpb = 24 * nz;                  // blocks per bh
  const int slot = n >> 3;
  const int bh = (n & 7) * 4 + slot / bpb;
  const int rm = slot % bpb;
  const int it = rm % 24, z = rm / 24;
  const int i0 = it * 64;
  const int b = bh >> 3, h = bh & 7;
  const int tid = threadIdx.x;
  const int w = tid >> 6, lane = tid & 63, q = lane >> 4, s = lane & 15;

  __shared__ __align__(16) u16 Kt[64*64];     // 8 KB  (swizzled 16B chunks)
  __shared__ __align__(16) u16 Rt[128*64];    // 16 KB
  __shared__ __align__(16) u16 Vs[96*64];     // 12 KB
  __shared__ __align__(16) u16 Ps[4][16][72]; // 9.2 KB

  // Q fragments with biases folded
  Frag qwf[2], qrf[2];
  {
    const u16* qb = Qb + (((size_t)bh)*LQ + i0 + 16*w + s)*64;
    #pragma unroll
    for (int kf = 0; kf < 2; ++kf) {
      u16x8_t qraw = *(const u16x8_t*)(qb + kf*32 + q*8);
      #pragma unroll
      for (int j = 0; j < 8; ++j) {
        int d = kf*32 + q*8 + j;
        float qv = bf2f(qraw[j]);
        qwf[kf].u[j] = f2bf(qv + rwb[h*64 + d]);
        qrf[kf].u[j] = f2bf(qv + rrb[h*64 + d]);
      }
    }
  }

  const f32x4_t fz = {0.f, 0.f, 0.f, 0.f};
  float mrun[4], lrun[4];
  f32x4_t acco[6];
  #pragma unroll
  for (int r = 0; r < 4; ++r) { mrun[r] = -1e30f; lrun[r] = 0.f; }
  #pragma unroll
  for (int vs = 0; vs < 6; ++vs) acco[vs] = fz;

  const char* kcb = (const char*)(Kc + ((size_t)bh)*LQ*64);
  const char* vtb = (const char*)(Vt + ((size_t)bh)*96*LQ);
  const char* rkb = (const char*)(rK + ((size_t)h)*NPOSP*64);

  // swizzled fragment column (16B-chunk id) per kf: (kf*4+q) ^ (s&7)
  const int swz0 = (0*4 + q) ^ (s & 7);
  const int swz1 = (1*4 + q) ^ (s & 7);

  const int njt = 24 / nz;
  const int jt0 = z * njt;

  for (int jt = jt0; jt < jt0 + njt; ++jt) {
    const int j0 = jt * 64;
    const int k0 = j0 - i0 + (LQ - 64);

    // ---- bulk stage: K tile (512 chunks), rK band (1024), V tile (768)
    {
      const char* kg = kcb + (size_t)j0 * 128;
      #pragma unroll
      for (int c = 0; c < 2; ++c) {
        int ck = w*128 + c*64 + lane;
        int grow = ck >> 3, gcol = (ck & 7) ^ (grow & 7);
        async16(kg + (size_t)grow*128 + gcol*16, &Kt[(size_t)(w*128 + c*64)*8]);
      }
      const char* rg = rkb + (size_t)k0 * 128;
      #pragma unroll
      for (int c = 0; c < 4; ++c) {
        int ck = w*256 + c*64 + lane;
        int grow = ck >> 3, gcol = (ck & 7) ^ (grow & 7);
        async16(rg + (size_t)grow*128 + gcol*16, &Rt[(size_t)(w*256 + c*64)*8]);
      }
      const char* vg = vtb + (size_t)j0 * 2;
      #pragma unroll
      for (int c = 0; c < 3; ++c) {
        int ck = w*192 + c*64 + lane;
        int grow = ck >> 3, gcol = (ck & 7) ^ (grow & 7);
        async16(vg + (size_t)grow*(LQ*2) + gcol*16, &Vs[(size_t)(w*192 + c*64)*8]);
      }
    }
    __syncthreads();   // drain DMA; all waves see staged tiles

    // ---- content scores: 16x64 per wave (B-frags from Kt)
    f32x4_t accc[4] = {fz, fz, fz, fz};
    #pragma unroll
    for (int ns = 0; ns < 4; ++ns) {
      int row = ns*16 + s;
      Frag b0; b0.u = *(const u16x8_t*)&Kt[(size_t)(row*8 + swz0)*8];
      Frag b1; b1.u = *(const u16x8_t*)&Kt[(size_t)(row*8 + swz1)*8];
      accc[ns] = __builtin_amdgcn_mfma_f32_16x16x32_bf16(qwf[0].b, b0.b, accc[ns], 0, 0, 0);
      accc[ns] = __builtin_amdgcn_mfma_f32_16x16x32_bf16(qwf[1].b, b1.b, accc[ns], 0, 0, 0);
    }

    // ---- rel band scores: 16 x 80 (subtiles 3-w..7-w of 128 band rows)
    f32x4_t accr[5] = {fz, fz, fz, fz, fz};
    #pragma unroll
    for (int nn = 0; nn < 5; ++nn) {
      int row = (3 - w + nn)*16 + s;
      Frag b0; b0.u = *(const u16x8_t*)&Rt[(size_t)(row*8 + swz0)*8];
      Frag b1; b1.u = *(const u16x8_t*)&Rt[(size_t)(row*8 + swz1)*8];
      accr[nn] = __builtin_amdgcn_mfma_f32_16x16x32_bf16(qrf[0].b, b0.b, accr[nn], 0, 0, 0);
      accr[nn] = __builtin_amdgcn_mfma_f32_16x16x32_bf16(qrf[1].b, b1.b, accr[nn], 0, 0, 0);
    }

    // ---- diagonal shift via bpermute: 5 source shuffles per row
    #pragma unroll
    for (int r = 0; r < 4; ++r) {
      int tt = s + 15 - 4*q - r;               // [0,30]
      int srcl = (lane & 48) | (tt & 15);
      bool hi = tt >= 16;
      float v[5];
      #pragma unroll
      for (int nn = 0; nn < 5; ++nn) v[nn] = __shfl(accr[nn][r], srcl, 64);
      #pragma unroll
      for (int ns = 0; ns < 4; ++ns)
        accc[ns][r] += hi ? v[ns + 1] : v[ns];
    }

    // ---- online softmax (in place on accc)
    #pragma unroll
    for (int r = 0; r < 4; ++r) {
      float mx = fmaxf(fmaxf(accc[0][r], accc[1][r]), fmaxf(accc[2][r], accc[3][r]));
      for (int d = 1; d < 16; d <<= 1) mx = fmaxf(mx, __shfl_xor(mx, d, 64));
      float mnew  = fmaxf(mrun[r], mx);
      float alpha = __expf(mrun[r] - mnew);
      float sum = 0.f;
      #pragma unroll
      for (int ns = 0; ns < 4; ++ns) {
        float p = __expf(accc[ns][r] - mnew);
        accc[ns][r] = p; sum += p;
      }
      for (int d = 1; d < 16; d <<= 1) sum += __shfl_xor(sum, d, 64);
      mrun[r] = mnew;
      lrun[r] = lrun[r]*alpha + sum;
      #pragma unroll
      for (int vs = 0; vs < 6; ++vs) acco[vs][r] *= alpha;
    }

    // ---- P: C-layout -> per-wave LDS -> A-layout (same wave, no barrier)
    #pragma unroll
    for (int ns = 0; ns < 4; ++ns)
      #pragma unroll
      for (int r = 0; r < 4; ++r)
        Ps[w][q*4 + r][ns*16 + s] = f2bf(accc[ns][r]);

    // ---- PV: P(16x64) @ V(64x96), V B-frags from Vs
    #pragma unroll
    for (int kf = 0; kf < 2; ++kf) {
      Frag pf; pf.u = *(const u16x8_t*)(&Ps[w][s][kf*32 + q*8]);
      int swz = kf ? swz1 : swz0;
      #pragma unroll
      for (int vs = 0; vs < 6; ++vs) {
        int row = vs*16 + s;
        Frag vf; vf.u = *(const u16x8_t*)&Vs[(size_t)(row*8 + swz)*8];
        acco[vs] = __builtin_amdgcn_mfma_f32_16x16x32_bf16(pf.b, vf.b, acco[vs], 0, 0, 0);
      }
    }
    __syncthreads();   // protect LDS tiles until all waves done
  }

  // ---- epilogue
  if (nz == 1) {
    #pragma unroll
    for (int vs = 0; vs < 6; ++vs) {
      int v = vs*16 + s;
      #pragma unroll
      for (int r = 0; r < 4; ++r) {
        int i = i0 + 16*w + q*4 + r;
        attnO[((size_t)b*LQ + i)*768 + h*96 + v] = f2bf(acco[vs][r] / lrun[r]);
      }
    }
  } else {
    #pragma unroll
    for (int vs = 0; vs < 6; ++vs) {
      int v = vs*16 + s;
      #pragma unroll
      for (int r = 0; r < 4; ++r) {
        int i = i0 + 16*w + q*4 + r;
        size_t rg = (size_t)(z*32 + bh)*LQ + i;
        Opart[rg*96 + v] = f2bf(acco[vs][r]);
      }
    }
    if (s == 0) {
      #pragma unroll
      for (int r = 0; r < 4; ++r) {
        int i = i0 + 16*w + q*4 + r;
        size_t rg = (size_t)(z*32 + bh)*LQ + i;
        ml[rg*2 + 0] = mrun[r];
        ml[rg*2 + 1] = lrun[r];
      }
    }
  }
}

// ---------------------------------------------------------------------------
// K5b: flash combine of nz j-partials -> attnO bf16. grid 18432 x 256.
// ---------------------------------------------------------------------------
__global__ void combine_k(const u16* __restrict__ Opart, const float* __restrict__ ml,
                          u16* __restrict__ attnO, int nz)
{
  int g = blockIdx.x * 256 + threadIdx.x;
  if (g >= 32*LQ*96) return;
  int v = g % 96, row = g / 96;
  int bh = row / LQ, i = row - bh*LQ;
  int b = bh >> 3, h = bh & 7;
  float M = -1e30f;
  for (int z = 0; z < nz; ++z)
    M = fmaxf(M, ml[((size_t)(z*32 + bh)*LQ + i)*2]);
  float L = 0.f, num = 0.f;
  for (int z = 0; z < nz; ++z) {
    size_t rg = (size_t)(z*32 + bh)*LQ + i;
    float e = __expf(ml[rg*2] - M);
    L   += ml[rg*2 + 1] * e;
    num += bf2f(Opart[rg*96 + v]) * e;
  }
  attnO[((size_t)b*LQ + i)*768 + h*96 + v] = f2bf(num / L);
}

// ---------------------------------------------------------------------------
// K6: output projection (M=6144, N=768, K=768) + bias -> d_out FLOAT
// ---------------------------------------------------------------------------
__global__ __launch_bounds__(256) void out_gemm(
    const u16* __restrict__ A, const u16* __restrict__ Wt,
    const float* __restrict__ bias, float* __restrict__ out)
{
  const int n0 = blockIdx.x * 64;
  const int m0 = blockIdx.y * 64;
  const int tid = threadIdx.x, w = tid >> 6, lane = tid & 63, q = lane >> 4, s = lane & 15;

  const u16* arow = A  + (size_t)(m0 + 16*w + s) * 768;
  const u16* brow = Wt + (size_t)n0 * 768;

  const f32x4_t fz = {0.f, 0.f, 0.f, 0.f};
  f32x4_t acc[4] = {fz, fz, fz, fz};

  for (int kk = 0; kk < 768; kk += 32) {
    Frag af; af.u = *(const u16x8_t*)(arow + kk + q*8);
    #pragma unroll
    for (int ns = 0; ns < 4; ++ns) {
      Frag bf; bf.u = *(const u16x8_t*)(brow + (size_t)(ns*16 + s)*768 + kk + q*8);
      acc[ns] = __builtin_amdgcn_mfma_f32_16x16x32_bf16(af.b, bf.b, acc[ns], 0, 0, 0);
    }
  }

  #pragma unroll
  for (int ns = 0; ns < 4; ++ns) {
    int c = n0 + ns*16 + s;
    float bv = bias[c];
    #pragma unroll
    for (int r = 0; r < 4; ++r) {
      int row = m0 + 16*w + q*4 + r;
      out[(size_t)row*768 + c] = acc[ns][r] + bv;
    }
  }
}

// ---------------------------------------------------------------------------
extern "C" void kernel_launch(void* const* d_in, const int* in_sizes, int n_in,
                              void* d_out, int out_size, void* d_ws, size_t ws_size,
                              hipStream_t stream)
{
  (void)out_size;

  static const int dict_sig[9] = {4718592,393216,393216,589824,589824,768,49152,512,512};
  bool is_dict = (n_in == 9);
  for (int i = 0; i < 9 && i < n_in; ++i)
    if (in_sizes[i] != dict_sig[i]) is_dict = false;

  const float *x, *Qw_w, *Kw_w, *Vw_w, *Ow_w, *out_b, *relKw, *rwb, *rrb;
  if (is_dict) {
    x     = (const float*)d_in[0];  Qw_w  = (const float*)d_in[1];
    Kw_w  = (const float*)d_in[2];  Vw_w  = (const float*)d_in[3];
    Ow_w  = (const float*)d_in[4];  out_b = (const float*)d_in[5];
    relKw = (const float*)d_in[6];  rwb   = (const float*)d_in[7];
    rrb   = (const float*)d_in[8];
  } else {
    const float* p393[2] = {nullptr,nullptr}; int n393 = 0;
    const float* p589[2] = {nullptr,nullptr}; int n589 = 0;
    const float* p512[2] = {nullptr,nullptr}; int n512 = 0;
    const float *px = nullptr, *prel = nullptr, *pb = nullptr;
    for (int i = 0; i < n_in; ++i) {
      const float* p = (const float*)d_in[i];
      switch (in_sizes[i]) {
        case 4718592: px = p; break;
        case 49152:   prel = p; break;
        case 768:     pb = p; break;
        case 393216:  if (n393 < 2) p393[n393++] = p; break;
        case 589824:  if (n589 < 2) p589[n589++] = p; break;
        case 512:     if (n512 < 2) p512[n512++] = p; break;
        default: break;
      }
    }
    x = px; relKw = prel; out_b = pb;
    Qw_w = p393[0]; Kw_w = p393[1];
    Vw_w = p589[0]; Ow_w = p589[1];
    rwb  = p512[0]; rrb  = p512[1];
  }

  float* out = (float*)d_out;

  char* ws = (char*)d_ws;
  size_t off = 0;
  auto alloc = [&](size_t bytes) -> void* {
    void* p = ws + off;
    off += (bytes + 255) & ~(size_t)255;
    return p;
  };

  float* gmax  = (float*)alloc(256);
  u16*   WtQKV = (u16*)  alloc((size_t)1792*768*2);   // 2.75 MB
  u16*   WtOut = (u16*)  alloc((size_t)768*768*2);    // 1.18 MB
  u16*   rK    = (u16*)  alloc((size_t)8*NPOSP*64*2); // 3 MB
  u16*   Qb    = (u16*)  alloc((size_t)32*LQ*64*2);   // 6.3 MB
  u16*   Kc    = (u16*)  alloc((size_t)32*LQ*64*2);   // 6.3 MB
  u16*   Vt    = (u16*)  alloc((size_t)32*96*LQ*2);   // 9.4 MB
  u16*   xb    = (u16*)  alloc((size_t)6144*768*2);   // 9.4 MB
  u16*   attnO = xb;  // alias: xb dead after qkv_gemm
  size_t off_before_part = off;
  u16*   Opart = (u16*)  alloc((size_t)2*32*LQ*96*2); // 18.9 MB
  float* ml    = (float*)alloc((size_t)2*32*LQ*2*4);  // 0.8 MB
  int nz = (ws_size >= off) ? 2 : 1;
  if (nz == 1) off = off_before_part;

  cvt_x      <<<dim3(4608), dim3(256), 0, stream>>>(x, xb);
  transpose_w<<<dim3(2560), dim3(256), 0, stream>>>(Qw_w, Kw_w, Vw_w, Ow_w, WtQKV, WtOut);
  gamma_max_k<<<dim3(16),   dim3(256), 0, stream>>>(gmax);
  rk_k       <<<dim3(NPOSP),dim3(256), 0, stream>>>(gmax, relKw, rK);
  qkv_gemm   <<<dim3(28,96),dim3(256), 0, stream>>>(xb, WtQKV, Qb, Kc, Vt);
  attn_k     <<<dim3(768*nz),dim3(256), 0, stream>>>(Qb, Kc, Vt, rK, rwb, rrb,
                                                     attnO, Opart, ml, nz);
  if (nz == 2)
    combine_k<<<dim3(18432), dim3(256), 0, stream>>>(Opart, ml, attnO, nz);
  out_gemm   <<<dim3(12,96),dim3(256), 0, stream>>>(attnO, WtOut, out_b, out);
}

// Round 9
// 430.663 us; speedup vs baseline: 1.4007x; 1.2443x over previous
//
#include <hip/hip_runtime.h>

// ---------------------------------------------------------------------------
// MHSelfAttention (Transformer-XL relative shift), MI355X gfx950
// B=4 L=1536 D=768 H=8 DQK=64 DV=96 NPF=96
// logits[b,h,i,j] = (Q*s+rwb)[i].K[j] + (Q*s+rrb)[i].rK[j-i+L-1]
// R9: attn_k LDS 50->33KB (drop V stage; direct V frags, L1-shared across
// waves) for 4 blocks/CU; qkv/out GEMMs get m97-style A+B LDS staging (BK=64);
// transpose_w rebuilt as coalesced LDS-tiled transpose. Inputs f32; out f32.
// ---------------------------------------------------------------------------

typedef unsigned short u16;
typedef unsigned int   u32;

typedef __bf16 bf16x8_t __attribute__((ext_vector_type(8)));
typedef unsigned short u16x8_t __attribute__((ext_vector_type(8)));
typedef float f32x4_t __attribute__((ext_vector_type(4)));

union Frag { u16x8_t u; bf16x8_t b; };

__device__ __forceinline__ float bf2f(u16 v){
  union { u32 i; float f; } c; c.i = ((u32)v) << 16; return c.f;
}
__device__ __forceinline__ u16 f2bf(float f){
  union { float f; u32 i; } c; c.f = f;
  u32 r = c.i + 0x7FFFu + ((c.i >> 16) & 1u);
  return (u16)(r >> 16);
}

#define GLB __attribute__((address_space(1)))
#define LDSAS __attribute__((address_space(3)))
__device__ __forceinline__ void async16(const void* g, void* l){
  __builtin_amdgcn_global_load_lds((const GLB u32*)g, (LDSAS u32*)l, 16, 0, 0);
}

#define LQ   1536
#define NPOS 3071   // 2L-1
#define NPOSP 3072  // row stride (row 3071 zeroed; indices j-i+1535 <= 3070)

// ---------------------------------------------------------------------------
// K0a: x (f32) -> bf16 staging. grid 4608 x 256, 4 elems/thread
// ---------------------------------------------------------------------------
__global__ void cvt_x(const float* __restrict__ x, u16* __restrict__ xb)
{
  int gid = blockIdx.x * 256 + threadIdx.x;
  float4 v = ((const float4*)x)[gid];
  xb[4*gid+0] = f2bf(v.x); xb[4*gid+1] = f2bf(v.y);
  xb[4*gid+2] = f2bf(v.z); xb[4*gid+3] = f2bf(v.w);
}

// ---------------------------------------------------------------------------
// K0b: coalesced LDS-tiled weight transpose -> K-major bf16.
// grid 480: blocks 0..335 cover QKV (28 c-tiles x 12 k-tiles),
// 336..479 cover Out (12 x 12). 64x64 f32 tile; read coalesced along c,
// write coalesced along k.
// ---------------------------------------------------------------------------
__global__ __launch_bounds__(256) void transpose_w(
    const float* __restrict__ Qw_, const float* __restrict__ Kw_,
    const float* __restrict__ Vw_, const float* __restrict__ Ow_,
    u16* __restrict__ WtQKV, u16* __restrict__ WtOut)
{
  __shared__ u16 tile[64][65];
  int bx = blockIdx.x;
  const float* src; int stride, cl0, c0, k0; u16* dst;
  if (bx < 336) {
    int ct = bx % 28, kt = bx / 28;
    c0 = ct*64; k0 = kt*64;
    if (c0 < 512)       { src = Qw_; stride = 512; cl0 = c0; }
    else if (c0 < 1024) { src = Kw_; stride = 512; cl0 = c0 - 512; }
    else                { src = Vw_; stride = 768; cl0 = c0 - 1024; }
    dst = WtQKV;
  } else {
    int b2 = bx - 336; int ct = b2 % 12, kt = b2 / 12;
    c0 = ct*64; k0 = kt*64; src = Ow_; stride = 768; cl0 = c0; dst = WtOut;
  }
  int t = threadIdx.x;
  #pragma unroll
  for (int e = 0; e < 16; ++e) {
    int idx = e*256 + t; int row = idx >> 6, col = idx & 63;
    tile[row][col] = f2bf(src[(size_t)(k0 + row)*stride + cl0 + col]);
  }
  __syncthreads();
  #pragma unroll
  for (int e = 0; e < 16; ++e) {
    int idx = e*256 + t; int orow = idx >> 6, ocol = idx & 63;
    dst[(size_t)(c0 + orow)*768 + k0 + ocol] = tile[ocol][orow];
  }
}

// ---------------------------------------------------------------------------
// K1: per-gamma-feature max over |pos| in [0,1535]   (16 blocks x 256)
// ---------------------------------------------------------------------------
__global__ void gamma_max_k(float* __restrict__ gmax)
{
  int f = blockIdx.x;
  float fi   = (float)(f + 1);
  float conc = 4.0f * fi * fi;
  float rate = fi / 24.0f;
  float c1   = conc - 1.0f;
  float lognorm = lgammaf(conc) - conc * logf(rate);
  float mx = 0.0f;
  for (int x = threadIdx.x; x < 1536; x += 256) {
    float xf = (float)x;
    float lu = (x == 0) ? -INFINITY : (c1 * logf(xf) - rate * xf);
    float p  = expf(lu - lognorm) + 1e-8f;
    mx = fmaxf(mx, p);
  }
  for (int d = 1; d < 64; d <<= 1) mx = fmaxf(mx, __shfl_xor(mx, d, 64));
  __shared__ float red[4];
  if ((threadIdx.x & 63) == 0) red[threadIdx.x >> 6] = mx;
  __syncthreads();
  if (threadIdx.x == 0)
    gmax[f] = fmaxf(fmaxf(red[0], red[1]), fmaxf(red[2], red[3]));
}

// ---------------------------------------------------------------------------
// K2: rK[h][k][d] = sum_f pe_feats(k)[f] * relKw[f][h*64+d], bf16 (8,3072,64)
// ---------------------------------------------------------------------------
__global__ void rk_k(const float* __restrict__ gmax,
                     const float* __restrict__ relKw, u16* __restrict__ rK)
{
  int k = blockIdx.x;
  int t = threadIdx.x;
  if (k == NPOS) {
    for (int c = t; c < 512; c += 256)
      rK[(((size_t)(c >> 6))*NPOSP + NPOS)*64 + (c & 63)] = 0;
    return;
  }
  __shared__ float feats[96];
  float pos = (float)(k - (LQ - 1));
  float x   = fabsf(pos);
  float sgn = (float)((pos > 0.0f) - (pos < 0.0f));
  if (t < 96) {
    int tb = (t < 48) ? t : t - 48;
    float val;
    if (tb < 16) {
      float max_range = log2f((float)LQ);
      float hl = exp2f(3.0f + (float)tb * (max_range - 3.0f) / 15.0f);
      val = expf(-0.69314718056f / hl * x);
    } else if (tb < 32) {
      int i = tb - 16;
      float width = (float)(1u << (i + 1)) - 1.0f;
      val = (width > x) ? 1.0f : 0.0f;
    } else {
      int i = tb - 32;
      float fi   = (float)(i + 1);
      float conc = 4.0f * fi * fi;
      float rate = fi / 24.0f;
      float lognorm = lgammaf(conc) - conc * logf(rate);
      float lu = (x == 0.0f) ? -INFINITY : ((conc - 1.0f) * logf(x) - rate * x);
      float p  = expf(lu - lognorm) + 1e-8f;
      val = p / gmax[i];
    }
    feats[t] = (t < 48) ? val : sgn * val;
  }
  __syncthreads();
  for (int c = t; c < 512; c += 256) {
    float acc = 0.0f;
    #pragma unroll 8
    for (int f = 0; f < 96; ++f) acc += feats[f] * relKw[(size_t)f*512 + c];
    rK[(((size_t)(c >> 6))*NPOSP + k)*64 + (c & 63)] = f2bf(acc);
  }
}

// ---------------------------------------------------------------------------
// K4: fused QKV projection GEMM (M=6144, N=1792, K=768), MFMA 16x16x32 bf16,
// m97-style A+B LDS staging (BK=64, XOR-swizzled 16B chunks). grid (28,96).
// ---------------------------------------------------------------------------
__global__ __launch_bounds__(256) void qkv_gemm(
    const u16* __restrict__ xb, const u16* __restrict__ Wt,
    u16* __restrict__ Qb, u16* __restrict__ Kc, u16* __restrict__ Vt)
{
  const int n0 = blockIdx.x * 64;
  const int m0 = blockIdx.y * 64;
  const int tid = threadIdx.x, w = tid >> 6, lane = tid & 63, q = lane >> 4, s = lane & 15;

  __shared__ __align__(16) u16 At[64*64];   // 8 KB
  __shared__ __align__(16) u16 Bt[64*64];   // 8 KB

  const char* ag = (const char*)(xb + (size_t)m0 * 768);
  const char* bg = (const char*)(Wt + (size_t)n0 * 768);

  const f32x4_t fz = {0.f, 0.f, 0.f, 0.f};
  f32x4_t acc[4] = {fz, fz, fz, fz};

  for (int kk = 0; kk < 768; kk += 64) {
    #pragma unroll
    for (int c = 0; c < 2; ++c) {
      int ck = w*128 + c*64 + lane;
      int grow = ck >> 3, gcol = (ck & 7) ^ (grow & 7);
      async16(ag + (size_t)grow*1536 + (size_t)(kk + gcol*8)*2, &At[(size_t)(w*128 + c*64)*8]);
      async16(bg + (size_t)grow*1536 + (size_t)(kk + gcol*8)*2, &Bt[(size_t)(w*128 + c*64)*8]);
    }
    __syncthreads();
    #pragma unroll
    for (int kf = 0; kf < 2; ++kf) {
      int sw = (kf*4 + q) ^ (s & 7);
      Frag af; af.u = *(const u16x8_t*)&At[(size_t)((16*w + s)*8 + sw)*8];
      #pragma unroll
      for (int ns = 0; ns < 4; ++ns) {
        Frag bf; bf.u = *(const u16x8_t*)&Bt[(size_t)((ns*16 + s)*8 + sw)*8];
        acc[ns] = __builtin_amdgcn_mfma_f32_16x16x32_bf16(af.b, bf.b, acc[ns], 0, 0, 0);
      }
    }
    __syncthreads();
  }

  #pragma unroll
  for (int ns = 0; ns < 4; ++ns) {
    int c = n0 + ns*16 + s;
    #pragma unroll
    for (int r = 0; r < 4; ++r) {
      int row = m0 + 16*w + q*4 + r;
      int b = row / LQ, i = row - b*LQ;
      float v = acc[ns][r];
      if (c < 512) {
        int h = c >> 6, d = c & 63;
        Qb[(((size_t)(b*8 + h))*LQ + i)*64 + d] = f2bf(v * 0.125f);
      } else if (c < 1024) {
        int cc = c - 512, h = cc >> 6, d = cc & 63;
        Kc[(((size_t)(b*8 + h))*LQ + i)*64 + d] = f2bf(v);
      } else {
        int cc = c - 1024, h = cc / 96, vv = cc - h*96;
        Vt[(((size_t)(b*8 + h))*96 + vv)*LQ + i] = f2bf(v);
      }
    }
  }
}

// ---------------------------------------------------------------------------
// K5: fused attention. K/rK LDS-staged (global_load_lds w=16, XOR-swizzled);
// V fragments direct from global (same rows for all 4 waves -> L1 hits,
// overlap softmax). LDS 33 KB -> 4 blocks/CU. XCD swizzle: each XCD owns 4 bh.
// ---------------------------------------------------------------------------
__global__ __launch_bounds__(256) void attn_k(
    const u16* __restrict__ Qb, const u16* __restrict__ Kc,
    const u16* __restrict__ Vt, const u16* __restrict__ rK,
    const float* __restrict__ rwb, const float* __restrict__ rrb,
    u16* __restrict__ attnO, u16* __restrict__ Opart, float* __restrict__ ml,
    int nz)
{
  const int n = blockIdx.x;
  const int bpb = 24 * nz;
  const int slot = n >> 3;
  const int bh = (n & 7) * 4 + slot / bpb;
  const int rm = slot % bpb;
  const int it = rm % 24, z = rm / 24;
  const int i0 = it * 64;
  const int b = bh >> 3, h = bh & 7;
  const int tid = threadIdx.x;
  const int w = tid >> 6, lane = tid & 63, q = lane >> 4, s = lane & 15;

  __shared__ __align__(16) u16 Kt[64*64];     // 8 KB  (swizzled 16B chunks)
  __shared__ __align__(16) u16 Rt[128*64];    // 16 KB
  __shared__ __align__(16) u16 Ps[4][16][72]; // 9.2 KB

  // Q fragments with biases folded
  Frag qwf[2], qrf[2];
  {
    const u16* qb = Qb + (((size_t)bh)*LQ + i0 + 16*w + s)*64;
    #pragma unroll
    for (int kf = 0; kf < 2; ++kf) {
      u16x8_t qraw = *(const u16x8_t*)(qb + kf*32 + q*8);
      #pragma unroll
      for (int j = 0; j < 8; ++j) {
        int d = kf*32 + q*8 + j;
        float qv = bf2f(qraw[j]);
        qwf[kf].u[j] = f2bf(qv + rwb[h*64 + d]);
        qrf[kf].u[j] = f2bf(qv + rrb[h*64 + d]);
      }
    }
  }

  const f32x4_t fz = {0.f, 0.f, 0.f, 0.f};
  float mrun[4], lrun[4];
  f32x4_t acco[6];
  #pragma unroll
  for (int r = 0; r < 4; ++r) { mrun[r] = -1e30f; lrun[r] = 0.f; }
  #pragma unroll
  for (int vs = 0; vs < 6; ++vs) acco[vs] = fz;

  const char* kcb = (const char*)(Kc + ((size_t)bh)*LQ*64);
  const u16*  vtb = Vt + ((size_t)bh)*96*LQ;
  const char* rkb = (const char*)(rK + ((size_t)h)*NPOSP*64);

  const int swz0 = (0*4 + q) ^ (s & 7);
  const int swz1 = (1*4 + q) ^ (s & 7);

  const int njt = 24 / nz;
  const int jt0 = z * njt;

  for (int jt = jt0; jt < jt0 + njt; ++jt) {
    const int j0 = jt * 64;
    const int k0 = j0 - i0 + (LQ - 64);

    // ---- bulk stage: K tile (512 chunks), rK band (1024 chunks)
    {
      const char* kg = kcb + (size_t)j0 * 128;
      #pragma unroll
      for (int c = 0; c < 2; ++c) {
        int ck = w*128 + c*64 + lane;
        int grow = ck >> 3, gcol = (ck & 7) ^ (grow & 7);
        async16(kg + (size_t)grow*128 + gcol*16, &Kt[(size_t)(w*128 + c*64)*8]);
      }
      const char* rg = rkb + (size_t)k0 * 128;
      #pragma unroll
      for (int c = 0; c < 4; ++c) {
        int ck = w*256 + c*64 + lane;
        int grow = ck >> 3, gcol = (ck & 7) ^ (grow & 7);
        async16(rg + (size_t)grow*128 + gcol*16, &Rt[(size_t)(w*256 + c*64)*8]);
      }
    }
    __syncthreads();   // drain DMA

    // ---- content scores: 16x64 per wave (B-frags from Kt)
    f32x4_t accc[4] = {fz, fz, fz, fz};
    #pragma unroll
    for (int ns = 0; ns < 4; ++ns) {
      int row = ns*16 + s;
      Frag b0; b0.u = *(const u16x8_t*)&Kt[(size_t)(row*8 + swz0)*8];
      Frag b1; b1.u = *(const u16x8_t*)&Kt[(size_t)(row*8 + swz1)*8];
      accc[ns] = __builtin_amdgcn_mfma_f32_16x16x32_bf16(qwf[0].b, b0.b, accc[ns], 0, 0, 0);
      accc[ns] = __builtin_amdgcn_mfma_f32_16x16x32_bf16(qwf[1].b, b1.b, accc[ns], 0, 0, 0);
    }

    // ---- rel band scores: 16 x 80 (subtiles 3-w..7-w of 128 band rows)
    f32x4_t accr[5] = {fz, fz, fz, fz, fz};
    #pragma unroll
    for (int nn = 0; nn < 5; ++nn) {
      int row = (3 - w + nn)*16 + s;
      Frag b0; b0.u = *(const u16x8_t*)&Rt[(size_t)(row*8 + swz0)*8];
      Frag b1; b1.u = *(const u16x8_t*)&Rt[(size_t)(row*8 + swz1)*8];
      accr[nn] = __builtin_amdgcn_mfma_f32_16x16x32_bf16(qrf[0].b, b0.b, accr[nn], 0, 0, 0);
      accr[nn] = __builtin_amdgcn_mfma_f32_16x16x32_bf16(qrf[1].b, b1.b, accr[nn], 0, 0, 0);
    }

    // ---- diagonal shift via bpermute
    #pragma unroll
    for (int r = 0; r < 4; ++r) {
      int tt = s + 15 - 4*q - r;               // [0,30]
      int srcl = (lane & 48) | (tt & 15);
      bool hi = tt >= 16;
      float v[5];
      #pragma unroll
      for (int nn = 0; nn < 5; ++nn) v[nn] = __shfl(accr[nn][r], srcl, 64);
      #pragma unroll
      for (int ns = 0; ns < 4; ++ns)
        accc[ns][r] += hi ? v[ns + 1] : v[ns];
    }

    // ---- online softmax (in place on accc)
    #pragma unroll
    for (int r = 0; r < 4; ++r) {
      float mx = fmaxf(fmaxf(accc[0][r], accc[1][r]), fmaxf(accc[2][r], accc[3][r]));
      for (int d = 1; d < 16; d <<= 1) mx = fmaxf(mx, __shfl_xor(mx, d, 64));
      float mnew  = fmaxf(mrun[r], mx);
      float alpha = __expf(mrun[r] - mnew);
      float sum = 0.f;
      #pragma unroll
      for (int ns = 0; ns < 4; ++ns) {
        float p = __expf(accc[ns][r] - mnew);
        accc[ns][r] = p; sum += p;
      }
      for (int d = 1; d < 16; d <<= 1) sum += __shfl_xor(sum, d, 64);
      mrun[r] = mnew;
      lrun[r] = lrun[r]*alpha + sum;
      #pragma unroll
      for (int vs = 0; vs < 6; ++vs) acco[vs][r] *= alpha;
    }

    // ---- P: C-layout -> per-wave LDS -> A-layout (same wave, no barrier)
    #pragma unroll
    for (int ns = 0; ns < 4; ++ns)
      #pragma unroll
      for (int r = 0; r < 4; ++r)
        Ps[w][q*4 + r][ns*16 + s] = f2bf(accc[ns][r]);

    // ---- PV: P(16x64) @ V(64x96), V frags direct from global (L1-shared)
    #pragma unroll
    for (int kf = 0; kf < 2; ++kf) {
      Frag pf; pf.u = *(const u16x8_t*)(&Ps[w][s][kf*32 + q*8]);
      #pragma unroll
      for (int vs = 0; vs < 6; ++vs) {
        Frag vf; vf.u = *(const u16x8_t*)(vtb + (size_t)(vs*16 + s)*LQ + j0 + kf*32 + q*8);
        acco[vs] = __builtin_amdgcn_mfma_f32_16x16x32_bf16(pf.b, vf.b, acco[vs], 0, 0, 0);
      }
    }
    __syncthreads();   // protect Kt/Rt until all waves done
  }

  // ---- epilogue
  if (nz == 1) {
    #pragma unroll
    for (int vs = 0; vs < 6; ++vs) {
      int v = vs*16 + s;
      #pragma unroll
      for (int r = 0; r < 4; ++r) {
        int i = i0 + 16*w + q*4 + r;
        attnO[((size_t)b*LQ + i)*768 + h*96 + v] = f2bf(acco[vs][r] / lrun[r]);
      }
    }
  } else {
    #pragma unroll
    for (int vs = 0; vs < 6; ++vs) {
      int v = vs*16 + s;
      #pragma unroll
      for (int r = 0; r < 4; ++r) {
        int i = i0 + 16*w + q*4 + r;
        size_t rg = (size_t)(z*32 + bh)*LQ + i;
        Opart[rg*96 + v] = f2bf(acco[vs][r]);
      }
    }
    if (s == 0) {
      #pragma unroll
      for (int r = 0; r < 4; ++r) {
        int i = i0 + 16*w + q*4 + r;
        size_t rg = (size_t)(z*32 + bh)*LQ + i;
        ml[rg*2 + 0] = mrun[r];
        ml[rg*2 + 1] = lrun[r];
      }
    }
  }
}

// ---------------------------------------------------------------------------
// K5b: flash combine of nz j-partials -> attnO bf16. grid 18432 x 256.
// ---------------------------------------------------------------------------
__global__ void combine_k(const u16* __restrict__ Opart, const float* __restrict__ ml,
                          u16* __restrict__ attnO, int nz)
{
  int g = blockIdx.x * 256 + threadIdx.x;
  if (g >= 32*LQ*96) return;
  int v = g % 96, row = g / 96;
  int bh = row / LQ, i = row - bh*LQ;
  int b = bh >> 3, h = bh & 7;
  float M = -1e30f;
  for (int z = 0; z < nz; ++z)
    M = fmaxf(M, ml[((size_t)(z*32 + bh)*LQ + i)*2]);
  float L = 0.f, num = 0.f;
  for (int z = 0; z < nz; ++z) {
    size_t rg = (size_t)(z*32 + bh)*LQ + i;
    float e = __expf(ml[rg*2] - M);
    L   += ml[rg*2 + 1] * e;
    num += bf2f(Opart[rg*96 + v]) * e;
  }
  attnO[((size_t)b*LQ + i)*768 + h*96 + v] = f2bf(num / L);
}

// ---------------------------------------------------------------------------
// K6: output projection (M=6144, N=768, K=768) + bias -> d_out FLOAT,
// same m97-style A+B staging. grid (12, 96).
// ---------------------------------------------------------------------------
__global__ __launch_bounds__(256) void out_gemm(
    const u16* __restrict__ A, const u16* __restrict__ Wt,
    const float* __restrict__ bias, float* __restrict__ out)
{
  const int n0 = blockIdx.x * 64;
  const int m0 = blockIdx.y * 64;
  const int tid = threadIdx.x, w = tid >> 6, lane = tid & 63, q = lane >> 4, s = lane & 15;

  __shared__ __align__(16) u16 At[64*64];
  __shared__ __align__(16) u16 Bt[64*64];

  const char* ag = (const char*)(A  + (size_t)m0 * 768);
  const char* bg = (const char*)(Wt + (size_t)n0 * 768);

  const f32x4_t fz = {0.f, 0.f, 0.f, 0.f};
  f32x4_t acc[4] = {fz, fz, fz, fz};

  for (int kk = 0; kk < 768; kk += 64) {
    #pragma unroll
    for (int c = 0; c < 2; ++c) {
      int ck = w*128 + c*64 + lane;
      int grow = ck >> 3, gcol = (ck & 7) ^ (grow & 7);
      async16(ag + (size_t)grow*1536 + (size_t)(kk + gcol*8)*2, &At[(size_t)(w*128 + c*64)*8]);
      async16(bg + (size_t)grow*1536 + (size_t)(kk + gcol*8)*2, &Bt[(size_t)(w*128 + c*64)*8]);
    }
    __syncthreads();
    #pragma unroll
    for (int kf = 0; kf < 2; ++kf) {
      int sw = (kf*4 + q) ^ (s & 7);
      Frag af; af.u = *(const u16x8_t*)&At[(size_t)((16*w + s)*8 + sw)*8];
      #pragma unroll
      for (int ns = 0; ns < 4; ++ns) {
        Frag bf; bf.u = *(const u16x8_t*)&Bt[(size_t)((ns*16 + s)*8 + sw)*8];
        acc[ns] = __builtin_amdgcn_mfma_f32_16x16x32_bf16(af.b, bf.b, acc[ns], 0, 0, 0);
      }
    }
    __syncthreads();
  }

  #pragma unroll
  for (int ns = 0; ns < 4; ++ns) {
    int c = n0 + ns*16 + s;
    float bv = bias[c];
    #pragma unroll
    for (int r = 0; r < 4; ++r) {
      int row = m0 + 16*w + q*4 + r;
      out[(size_t)row*768 + c] = acc[ns][r] + bv;
    }
  }
}

// ---------------------------------------------------------------------------
extern "C" void kernel_launch(void* const* d_in, const int* in_sizes, int n_in,
                              void* d_out, int out_size, void* d_ws, size_t ws_size,
                              hipStream_t stream)
{
  (void)out_size;

  static const int dict_sig[9] = {4718592,393216,393216,589824,589824,768,49152,512,512};
  bool is_dict = (n_in == 9);
  for (int i = 0; i < 9 && i < n_in; ++i)
    if (in_sizes[i] != dict_sig[i]) is_dict = false;

  const float *x, *Qw_w, *Kw_w, *Vw_w, *Ow_w, *out_b, *relKw, *rwb, *rrb;
  if (is_dict) {
    x     = (const float*)d_in[0];  Qw_w  = (const float*)d_in[1];
    Kw_w  = (const float*)d_in[2];  Vw_w  = (const float*)d_in[3];
    Ow_w  = (const float*)d_in[4];  out_b = (const float*)d_in[5];
    relKw = (const float*)d_in[6];  rwb   = (const float*)d_in[7];
    rrb   = (const float*)d_in[8];
  } else {
    const float* p393[2] = {nullptr,nullptr}; int n393 = 0;
    const float* p589[2] = {nullptr,nullptr}; int n589 = 0;
    const float* p512[2] = {nullptr,nullptr}; int n512 = 0;
    const float *px = nullptr, *prel = nullptr, *pb = nullptr;
    for (int i = 0; i < n_in; ++i) {
      const float* p = (const float*)d_in[i];
      switch (in_sizes[i]) {
        case 4718592: px = p; break;
        case 49152:   prel = p; break;
        case 768:     pb = p; break;
        case 393216:  if (n393 < 2) p393[n393++] = p; break;
        case 589824:  if (n589 < 2) p589[n589++] = p; break;
        case 512:     if (n512 < 2) p512[n512++] = p; break;
        default: break;
      }
    }
    x = px; relKw = prel; out_b = pb;
    Qw_w = p393[0]; Kw_w = p393[1];
    Vw_w = p589[0]; Ow_w = p589[1];
    rwb  = p512[0]; rrb  = p512[1];
  }

  float* out = (float*)d_out;

  char* ws = (char*)d_ws;
  size_t off = 0;
  auto alloc = [&](size_t bytes) -> void* {
    void* p = ws + off;
    off += (bytes + 255) & ~(size_t)255;
    return p;
  };

  float* gmax  = (float*)alloc(256);
  u16*   WtQKV = (u16*)  alloc((size_t)1792*768*2);   // 2.75 MB
  u16*   WtOut = (u16*)  alloc((size_t)768*768*2);    // 1.18 MB
  u16*   rK    = (u16*)  alloc((size_t)8*NPOSP*64*2); // 3 MB
  u16*   Qb    = (u16*)  alloc((size_t)32*LQ*64*2);   // 6.3 MB
  u16*   Kc    = (u16*)  alloc((size_t)32*LQ*64*2);   // 6.3 MB
  u16*   Vt    = (u16*)  alloc((size_t)32*96*LQ*2);   // 9.4 MB
  u16*   xb    = (u16*)  alloc((size_t)6144*768*2);   // 9.4 MB
  u16*   attnO = xb;  // alias: xb dead after qkv_gemm
  size_t off_before_part = off;
  u16*   Opart = (u16*)  alloc((size_t)2*32*LQ*96*2); // 18.9 MB
  float* ml    = (float*)alloc((size_t)2*32*LQ*2*4);  // 0.8 MB
  int nz = (ws_size >= off) ? 2 : 1;
  if (nz == 1) off = off_before_part;

  cvt_x      <<<dim3(4608), dim3(256), 0, stream>>>(x, xb);
  transpose_w<<<dim3(480),  dim3(256), 0, stream>>>(Qw_w, Kw_w, Vw_w, Ow_w, WtQKV, WtOut);
  gamma_max_k<<<dim3(16),   dim3(256), 0, stream>>>(gmax);
  rk_k       <<<dim3(NPOSP),dim3(256), 0, stream>>>(gmax, relKw, rK);
  qkv_gemm   <<<dim3(28,96),dim3(256), 0, stream>>>(xb, WtQKV, Qb, Kc, Vt);
  attn_k     <<<dim3(768*nz),dim3(256), 0, stream>>>(Qb, Kc, Vt, rK, rwb, rrb,
                                                     attnO, Opart, ml, nz);
  if (nz == 2)
    combine_k<<<dim3(18432), dim3(256), 0, stream>>>(Opart, ml, attnO, nz);
  out_gemm   <<<dim3(12,96),dim3(256), 0, stream>>>(attnO, WtOut, out_b, out);
}

// Round 10
// 342.810 us; speedup vs baseline: 1.7597x; 1.2563x over previous
//
#include <hip/hip_runtime.h>

// ---------------------------------------------------------------------------
// MHSelfAttention (Transformer-XL relative shift), MI355X gfx950
// B=4 L=1536 D=768 H=8 DQK=64 DV=96 NPF=96
// logits[b,h,i,j] = (Q*s+rwb)[i].K[j] + (Q*s+rrb)[i].rK[j-i+L-1]
// R10: attn_k = R8 full staging (K/rK/V via global_load_lds) generalized to
// 512-thread blocks, i-tile 128 (8 waves): staged bytes/MFMA 300->183,
// 16 waves/CU, half the barriers per i-row. nz=4 j-split. Others = R9.
// ---------------------------------------------------------------------------

typedef unsigned short u16;
typedef unsigned int   u32;

typedef __bf16 bf16x8_t __attribute__((ext_vector_type(8)));
typedef unsigned short u16x8_t __attribute__((ext_vector_type(8)));
typedef float f32x4_t __attribute__((ext_vector_type(4)));

union Frag { u16x8_t u; bf16x8_t b; };

__device__ __forceinline__ float bf2f(u16 v){
  union { u32 i; float f; } c; c.i = ((u32)v) << 16; return c.f;
}
__device__ __forceinline__ u16 f2bf(float f){
  union { float f; u32 i; } c; c.f = f;
  u32 r = c.i + 0x7FFFu + ((c.i >> 16) & 1u);
  return (u16)(r >> 16);
}

#define GLB __attribute__((address_space(1)))
#define LDSAS __attribute__((address_space(3)))
__device__ __forceinline__ void async16(const void* g, void* l){
  __builtin_amdgcn_global_load_lds((const GLB u32*)g, (LDSAS u32*)l, 16, 0, 0);
}

#define LQ   1536
#define NPOS 3071   // 2L-1
#define NPOSP 3072  // row stride (row 3071 zeroed; staged-but-unread at edge)

// ---------------------------------------------------------------------------
// K0a: x (f32) -> bf16 staging. grid 4608 x 256, 4 elems/thread
// ---------------------------------------------------------------------------
__global__ void cvt_x(const float* __restrict__ x, u16* __restrict__ xb)
{
  int gid = blockIdx.x * 256 + threadIdx.x;
  float4 v = ((const float4*)x)[gid];
  xb[4*gid+0] = f2bf(v.x); xb[4*gid+1] = f2bf(v.y);
  xb[4*gid+2] = f2bf(v.z); xb[4*gid+3] = f2bf(v.w);
}

// ---------------------------------------------------------------------------
// K0b: coalesced LDS-tiled weight transpose -> K-major bf16. grid 480.
// ---------------------------------------------------------------------------
__global__ __launch_bounds__(256) void transpose_w(
    const float* __restrict__ Qw_, const float* __restrict__ Kw_,
    const float* __restrict__ Vw_, const float* __restrict__ Ow_,
    u16* __restrict__ WtQKV, u16* __restrict__ WtOut)
{
  __shared__ u16 tile[64][65];
  int bx = blockIdx.x;
  const float* src; int stride, cl0, c0, k0; u16* dst;
  if (bx < 336) {
    int ct = bx % 28, kt = bx / 28;
    c0 = ct*64; k0 = kt*64;
    if (c0 < 512)       { src = Qw_; stride = 512; cl0 = c0; }
    else if (c0 < 1024) { src = Kw_; stride = 512; cl0 = c0 - 512; }
    else                { src = Vw_; stride = 768; cl0 = c0 - 1024; }
    dst = WtQKV;
  } else {
    int b2 = bx - 336; int ct = b2 % 12, kt = b2 / 12;
    c0 = ct*64; k0 = kt*64; src = Ow_; stride = 768; cl0 = c0; dst = WtOut;
  }
  int t = threadIdx.x;
  #pragma unroll
  for (int e = 0; e < 16; ++e) {
    int idx = e*256 + t; int row = idx >> 6, col = idx & 63;
    tile[row][col] = f2bf(src[(size_t)(k0 + row)*stride + cl0 + col]);
  }
  __syncthreads();
  #pragma unroll
  for (int e = 0; e < 16; ++e) {
    int idx = e*256 + t; int orow = idx >> 6, ocol = idx & 63;
    dst[(size_t)(c0 + orow)*768 + k0 + ocol] = tile[ocol][orow];
  }
}

// ---------------------------------------------------------------------------
// K1: per-gamma-feature max over |pos| in [0,1535]   (16 blocks x 256)
// ---------------------------------------------------------------------------
__global__ void gamma_max_k(float* __restrict__ gmax)
{
  int f = blockIdx.x;
  float fi   = (float)(f + 1);
  float conc = 4.0f * fi * fi;
  float rate = fi / 24.0f;
  float c1   = conc - 1.0f;
  float lognorm = lgammaf(conc) - conc * logf(rate);
  float mx = 0.0f;
  for (int x = threadIdx.x; x < 1536; x += 256) {
    float xf = (float)x;
    float lu = (x == 0) ? -INFINITY : (c1 * logf(xf) - rate * xf);
    float p  = expf(lu - lognorm) + 1e-8f;
    mx = fmaxf(mx, p);
  }
  for (int d = 1; d < 64; d <<= 1) mx = fmaxf(mx, __shfl_xor(mx, d, 64));
  __shared__ float red[4];
  if ((threadIdx.x & 63) == 0) red[threadIdx.x >> 6] = mx;
  __syncthreads();
  if (threadIdx.x == 0)
    gmax[f] = fmaxf(fmaxf(red[0], red[1]), fmaxf(red[2], red[3]));
}

// ---------------------------------------------------------------------------
// K2: rK[h][k][d] = sum_f pe_feats(k)[f] * relKw[f][h*64+d], bf16 (8,3072,64)
// ---------------------------------------------------------------------------
__global__ void rk_k(const float* __restrict__ gmax,
                     const float* __restrict__ relKw, u16* __restrict__ rK)
{
  int k = blockIdx.x;
  int t = threadIdx.x;
  if (k == NPOS) {
    for (int c = t; c < 512; c += 256)
      rK[(((size_t)(c >> 6))*NPOSP + NPOS)*64 + (c & 63)] = 0;
    return;
  }
  __shared__ float feats[96];
  float pos = (float)(k - (LQ - 1));
  float x   = fabsf(pos);
  float sgn = (float)((pos > 0.0f) - (pos < 0.0f));
  if (t < 96) {
    int tb = (t < 48) ? t : t - 48;
    float val;
    if (tb < 16) {
      float max_range = log2f((float)LQ);
      float hl = exp2f(3.0f + (float)tb * (max_range - 3.0f) / 15.0f);
      val = expf(-0.69314718056f / hl * x);
    } else if (tb < 32) {
      int i = tb - 16;
      float width = (float)(1u << (i + 1)) - 1.0f;
      val = (width > x) ? 1.0f : 0.0f;
    } else {
      int i = tb - 32;
      float fi   = (float)(i + 1);
      float conc = 4.0f * fi * fi;
      float rate = fi / 24.0f;
      float lognorm = lgammaf(conc) - conc * logf(rate);
      float lu = (x == 0.0f) ? -INFINITY : ((conc - 1.0f) * logf(x) - rate * x);
      float p  = expf(lu - lognorm) + 1e-8f;
      val = p / gmax[i];
    }
    feats[t] = (t < 48) ? val : sgn * val;
  }
  __syncthreads();
  for (int c = t; c < 512; c += 256) {
    float acc = 0.0f;
    #pragma unroll 8
    for (int f = 0; f < 96; ++f) acc += feats[f] * relKw[(size_t)f*512 + c];
    rK[(((size_t)(c >> 6))*NPOSP + k)*64 + (c & 63)] = f2bf(acc);
  }
}

// ---------------------------------------------------------------------------
// K4: fused QKV projection GEMM (M=6144, N=1792, K=768), A+B LDS staging.
// ---------------------------------------------------------------------------
__global__ __launch_bounds__(256) void qkv_gemm(
    const u16* __restrict__ xb, const u16* __restrict__ Wt,
    u16* __restrict__ Qb, u16* __restrict__ Kc, u16* __restrict__ Vt)
{
  const int n0 = blockIdx.x * 64;
  const int m0 = blockIdx.y * 64;
  const int tid = threadIdx.x, w = tid >> 6, lane = tid & 63, q = lane >> 4, s = lane & 15;

  __shared__ __align__(16) u16 At[64*64];
  __shared__ __align__(16) u16 Bt[64*64];

  const char* ag = (const char*)(xb + (size_t)m0 * 768);
  const char* bg = (const char*)(Wt + (size_t)n0 * 768);

  const f32x4_t fz = {0.f, 0.f, 0.f, 0.f};
  f32x4_t acc[4] = {fz, fz, fz, fz};

  for (int kk = 0; kk < 768; kk += 64) {
    #pragma unroll
    for (int c = 0; c < 2; ++c) {
      int ck = w*128 + c*64 + lane;
      int grow = ck >> 3, gcol = (ck & 7) ^ (grow & 7);
      async16(ag + (size_t)grow*1536 + (size_t)(kk + gcol*8)*2, &At[(size_t)(w*128 + c*64)*8]);
      async16(bg + (size_t)grow*1536 + (size_t)(kk + gcol*8)*2, &Bt[(size_t)(w*128 + c*64)*8]);
    }
    __syncthreads();
    #pragma unroll
    for (int kf = 0; kf < 2; ++kf) {
      int sw = (kf*4 + q) ^ (s & 7);
      Frag af; af.u = *(const u16x8_t*)&At[(size_t)((16*w + s)*8 + sw)*8];
      #pragma unroll
      for (int ns = 0; ns < 4; ++ns) {
        Frag bf; bf.u = *(const u16x8_t*)&Bt[(size_t)((ns*16 + s)*8 + sw)*8];
        acc[ns] = __builtin_amdgcn_mfma_f32_16x16x32_bf16(af.b, bf.b, acc[ns], 0, 0, 0);
      }
    }
    __syncthreads();
  }

  #pragma unroll
  for (int ns = 0; ns < 4; ++ns) {
    int c = n0 + ns*16 + s;
    #pragma unroll
    for (int r = 0; r < 4; ++r) {
      int row = m0 + 16*w + q*4 + r;
      int b = row / LQ, i = row - b*LQ;
      float v = acc[ns][r];
      if (c < 512) {
        int h = c >> 6, d = c & 63;
        Qb[(((size_t)(b*8 + h))*LQ + i)*64 + d] = f2bf(v * 0.125f);
      } else if (c < 1024) {
        int cc = c - 512, h = cc >> 6, d = cc & 63;
        Kc[(((size_t)(b*8 + h))*LQ + i)*64 + d] = f2bf(v);
      } else {
        int cc = c - 1024, h = cc / 96, vv = cc - h*96;
        Vt[(((size_t)(b*8 + h))*96 + vv)*LQ + i] = f2bf(v);
      }
    }
  }
}

// ---------------------------------------------------------------------------
// K5: fused attention, 512 threads (8 waves), i-tile 128, full LDS staging.
// grid 384*nz: bh = (n&7)*4 + slot/(12*nz); it = rm%12, z = rm/12.
// Per jt: stage K(64x64, 8KB) + rK band(192x64, 24KB) + V(96x64, 12KB) via
// global_load_lds w=16, XOR-swizzled chunks. Wave w owns i-rows 16w..16w+15;
// rel subtiles 7-w..11-w; diag shift tt=s+15-4q-r (same algebra as 4-wave).
// ---------------------------------------------------------------------------
__global__ __launch_bounds__(512, 4) void attn_k(
    const u16* __restrict__ Qb, const u16* __restrict__ Kc,
    const u16* __restrict__ Vt, const u16* __restrict__ rK,
    const float* __restrict__ rwb, const float* __restrict__ rrb,
    u16* __restrict__ attnO, u16* __restrict__ Opart, float* __restrict__ ml,
    int nz)
{
  const int n = blockIdx.x;
  const int bpb = 12 * nz;
  const int slot = n >> 3;
  const int bh = (n & 7) * 4 + slot / bpb;
  const int rm = slot % bpb;
  const int it = rm % 12, z = rm / 12;
  const int i0 = it * 128;
  const int b = bh >> 3, h = bh & 7;
  const int tid = threadIdx.x;
  const int w = tid >> 6, lane = tid & 63, q = lane >> 4, s = lane & 15;

  __shared__ __align__(16) u16 Kt[64*64];      // 8 KB
  __shared__ __align__(16) u16 Rt[192*64];     // 24 KB
  __shared__ __align__(16) u16 Vs[96*64];      // 12 KB
  __shared__ __align__(16) u16 Ps[8][16][72];  // 18 KB   (total 62 KB)

  // Q fragments with biases folded
  Frag qwf[2], qrf[2];
  {
    const u16* qb = Qb + (((size_t)bh)*LQ + i0 + 16*w + s)*64;
    #pragma unroll
    for (int kf = 0; kf < 2; ++kf) {
      u16x8_t qraw = *(const u16x8_t*)(qb + kf*32 + q*8);
      #pragma unroll
      for (int j = 0; j < 8; ++j) {
        int d = kf*32 + q*8 + j;
        float qv = bf2f(qraw[j]);
        qwf[kf].u[j] = f2bf(qv + rwb[h*64 + d]);
        qrf[kf].u[j] = f2bf(qv + rrb[h*64 + d]);
      }
    }
  }

  const f32x4_t fz = {0.f, 0.f, 0.f, 0.f};
  float mrun[4], lrun[4];
  f32x4_t acco[6];
  #pragma unroll
  for (int r = 0; r < 4; ++r) { mrun[r] = -1e30f; lrun[r] = 0.f; }
  #pragma unroll
  for (int vs = 0; vs < 6; ++vs) acco[vs] = fz;

  const char* kcb = (const char*)(Kc + ((size_t)bh)*LQ*64);
  const char* vtb = (const char*)(Vt + ((size_t)bh)*96*LQ);
  const char* rkb = (const char*)(rK + ((size_t)h)*NPOSP*64);

  const int swz0 = (0*4 + q) ^ (s & 7);
  const int swz1 = (1*4 + q) ^ (s & 7);

  const int njt = 24 / nz;
  const int jt0 = z * njt;

  for (int jt = jt0; jt < jt0 + njt; ++jt) {
    const int j0 = jt * 64;
    const int k0 = j0 - i0 + (LQ - 128);     // band base (>=0; max row 3071)

    // ---- bulk stage: K 512 chunks, rK 1536 chunks, V 768 chunks (16B each)
    {
      const char* kg = kcb + (size_t)j0 * 128;
      {
        int ck = tid;                                   // 512 chunks
        int grow = ck >> 3, gcol = (ck & 7) ^ (grow & 7);
        async16(kg + (size_t)grow*128 + gcol*16, &Kt[(size_t)(w*64)*8]);
      }
      const char* rg = rkb + (size_t)k0 * 128;
      #pragma unroll
      for (int c = 0; c < 3; ++c) {                     // 1536 chunks
        int ck = c*512 + tid;
        int grow = ck >> 3, gcol = (ck & 7) ^ (grow & 7);
        async16(rg + (size_t)grow*128 + gcol*16, &Rt[(size_t)(c*512 + w*64)*8]);
      }
      const char* vg = vtb + (size_t)j0 * 2;
      {
        int ck = tid;                                   // first 512 of 768
        int grow = ck >> 3, gcol = (ck & 7) ^ (grow & 7);
        async16(vg + (size_t)grow*(LQ*2) + gcol*16, &Vs[(size_t)(w*64)*8]);
      }
      if (tid < 256) {                                  // last 256 chunks
        int ck = 512 + tid;
        int grow = ck >> 3, gcol = (ck & 7) ^ (grow & 7);
        async16(vg + (size_t)grow*(LQ*2) + gcol*16, &Vs[(size_t)(512 + w*64)*8]);
      }
    }
    __syncthreads();   // drain DMA; all 8 waves see staged tiles

    // ---- content scores: 16x64 per wave (B-frags from Kt)
    f32x4_t accc[4] = {fz, fz, fz, fz};
    #pragma unroll
    for (int ns = 0; ns < 4; ++ns) {
      int row = ns*16 + s;
      Frag b0; b0.u = *(const u16x8_t*)&Kt[(size_t)(row*8 + swz0)*8];
      Frag b1; b1.u = *(const u16x8_t*)&Kt[(size_t)(row*8 + swz1)*8];
      accc[ns] = __builtin_amdgcn_mfma_f32_16x16x32_bf16(qwf[0].b, b0.b, accc[ns], 0, 0, 0);
      accc[ns] = __builtin_amdgcn_mfma_f32_16x16x32_bf16(qwf[1].b, b1.b, accc[ns], 0, 0, 0);
    }

    // ---- rel band scores: 16 x 80 (subtiles 7-w..11-w of 192 band rows)
    f32x4_t accr[5] = {fz, fz, fz, fz, fz};
    #pragma unroll
    for (int nn = 0; nn < 5; ++nn) {
      int row = (7 - w + nn)*16 + s;
      Frag b0; b0.u = *(const u16x8_t*)&Rt[(size_t)(row*8 + swz0)*8];
      Frag b1; b1.u = *(const u16x8_t*)&Rt[(size_t)(row*8 + swz1)*8];
      accr[nn] = __builtin_amdgcn_mfma_f32_16x16x32_bf16(qrf[0].b, b0.b, accr[nn], 0, 0, 0);
      accr[nn] = __builtin_amdgcn_mfma_f32_16x16x32_bf16(qrf[1].b, b1.b, accr[nn], 0, 0, 0);
    }

    // ---- diagonal shift via bpermute (same algebra; w-terms cancel)
    #pragma unroll
    for (int r = 0; r < 4; ++r) {
      int tt = s + 15 - 4*q - r;               // [0,30]
      int srcl = (lane & 48) | (tt & 15);
      bool hi = tt >= 16;
      float v[5];
      #pragma unroll
      for (int nn = 0; nn < 5; ++nn) v[nn] = __shfl(accr[nn][r], srcl, 64);
      #pragma unroll
      for (int ns = 0; ns < 4; ++ns)
        accc[ns][r] += hi ? v[ns + 1] : v[ns];
    }

    // ---- online softmax
    #pragma unroll
    for (int r = 0; r < 4; ++r) {
      float mx = fmaxf(fmaxf(accc[0][r], accc[1][r]), fmaxf(accc[2][r], accc[3][r]));
      for (int d = 1; d < 16; d <<= 1) mx = fmaxf(mx, __shfl_xor(mx, d, 64));
      float mnew  = fmaxf(mrun[r], mx);
      float alpha = __expf(mrun[r] - mnew);
      float sum = 0.f;
      #pragma unroll
      for (int ns = 0; ns < 4; ++ns) {
        float p = __expf(accc[ns][r] - mnew);
        accc[ns][r] = p; sum += p;
      }
      for (int d = 1; d < 16; d <<= 1) sum += __shfl_xor(sum, d, 64);
      mrun[r] = mnew;
      lrun[r] = lrun[r]*alpha + sum;
      #pragma unroll
      for (int vs = 0; vs < 6; ++vs) acco[vs][r] *= alpha;
    }

    // ---- P: C-layout -> per-wave LDS -> A-layout
    #pragma unroll
    for (int ns = 0; ns < 4; ++ns)
      #pragma unroll
      for (int r = 0; r < 4; ++r)
        Ps[w][q*4 + r][ns*16 + s] = f2bf(accc[ns][r]);

    // ---- PV: P(16x64) @ V(64x96), V B-frags from Vs
    #pragma unroll
    for (int kf = 0; kf < 2; ++kf) {
      Frag pf; pf.u = *(const u16x8_t*)(&Ps[w][s][kf*32 + q*8]);
      int sw = kf ? swz1 : swz0;
      #pragma unroll
      for (int vs = 0; vs < 6; ++vs) {
        int row = vs*16 + s;
        Frag vf; vf.u = *(const u16x8_t*)&Vs[(size_t)(row*8 + sw)*8];
        acco[vs] = __builtin_amdgcn_mfma_f32_16x16x32_bf16(pf.b, vf.b, acco[vs], 0, 0, 0);
      }
    }
    __syncthreads();   // protect staged tiles until all waves done
  }

  // ---- epilogue
  if (nz == 1) {
    #pragma unroll
    for (int vs = 0; vs < 6; ++vs) {
      int v = vs*16 + s;
      #pragma unroll
      for (int r = 0; r < 4; ++r) {
        int i = i0 + 16*w + q*4 + r;
        attnO[((size_t)b*LQ + i)*768 + h*96 + v] = f2bf(acco[vs][r] / lrun[r]);
      }
    }
  } else {
    #pragma unroll
    for (int vs = 0; vs < 6; ++vs) {
      int v = vs*16 + s;
      #pragma unroll
      for (int r = 0; r < 4; ++r) {
        int i = i0 + 16*w + q*4 + r;
        size_t rg = (size_t)(z*32 + bh)*LQ + i;
        Opart[rg*96 + v] = f2bf(acco[vs][r]);
      }
    }
    if (s == 0) {
      #pragma unroll
      for (int r = 0; r < 4; ++r) {
        int i = i0 + 16*w + q*4 + r;
        size_t rg = (size_t)(z*32 + bh)*LQ + i;
        ml[rg*2 + 0] = mrun[r];
        ml[rg*2 + 1] = lrun[r];
      }
    }
  }
}

// ---------------------------------------------------------------------------
// K5b: flash combine of nz j-partials -> attnO bf16. grid 18432 x 256.
// ---------------------------------------------------------------------------
__global__ void combine_k(const u16* __restrict__ Opart, const float* __restrict__ ml,
                          u16* __restrict__ attnO, int nz)
{
  int g = blockIdx.x * 256 + threadIdx.x;
  if (g >= 32*LQ*96) return;
  int v = g % 96, row = g / 96;
  int bh = row / LQ, i = row - bh*LQ;
  int b = bh >> 3, h = bh & 7;
  float M = -1e30f;
  for (int z = 0; z < nz; ++z)
    M = fmaxf(M, ml[((size_t)(z*32 + bh)*LQ + i)*2]);
  float L = 0.f, num = 0.f;
  for (int z = 0; z < nz; ++z) {
    size_t rg = (size_t)(z*32 + bh)*LQ + i;
    float e = __expf(ml[rg*2] - M);
    L   += ml[rg*2 + 1] * e;
    num += bf2f(Opart[rg*96 + v]) * e;
  }
  attnO[((size_t)b*LQ + i)*768 + h*96 + v] = f2bf(num / L);
}

// ---------------------------------------------------------------------------
// K6: output projection (M=6144, N=768, K=768) + bias -> d_out FLOAT.
// ---------------------------------------------------------------------------
__global__ __launch_bounds__(256) void out_gemm(
    const u16* __restrict__ A, const u16* __restrict__ Wt,
    const float* __restrict__ bias, float* __restrict__ out)
{
  const int n0 = blockIdx.x * 64;
  const int m0 = blockIdx.y * 64;
  const int tid = threadIdx.x, w = tid >> 6, lane = tid & 63, q = lane >> 4, s = lane & 15;

  __shared__ __align__(16) u16 At[64*64];
  __shared__ __align__(16) u16 Bt[64*64];

  const char* ag = (const char*)(A  + (size_t)m0 * 768);
  const char* bg = (const char*)(Wt + (size_t)n0 * 768);

  const f32x4_t fz = {0.f, 0.f, 0.f, 0.f};
  f32x4_t acc[4] = {fz, fz, fz, fz};

  for (int kk = 0; kk < 768; kk += 64) {
    #pragma unroll
    for (int c = 0; c < 2; ++c) {
      int ck = w*128 + c*64 + lane;
      int grow = ck >> 3, gcol = (ck & 7) ^ (grow & 7);
      async16(ag + (size_t)grow*1536 + (size_t)(kk + gcol*8)*2, &At[(size_t)(w*128 + c*64)*8]);
      async16(bg + (size_t)grow*1536 + (size_t)(kk + gcol*8)*2, &Bt[(size_t)(w*128 + c*64)*8]);
    }
    __syncthreads();
    #pragma unroll
    for (int kf = 0; kf < 2; ++kf) {
      int sw = (kf*4 + q) ^ (s & 7);
      Frag af; af.u = *(const u16x8_t*)&At[(size_t)((16*w + s)*8 + sw)*8];
      #pragma unroll
      for (int ns = 0; ns < 4; ++ns) {
        Frag bf; bf.u = *(const u16x8_t*)&Bt[(size_t)((ns*16 + s)*8 + sw)*8];
        acc[ns] = __builtin_amdgcn_mfma_f32_16x16x32_bf16(af.b, bf.b, acc[ns], 0, 0, 0);
      }
    }
    __syncthreads();
  }

  #pragma unroll
  for (int ns = 0; ns < 4; ++ns) {
    int c = n0 + ns*16 + s;
    float bv = bias[c];
    #pragma unroll
    for (int r = 0; r < 4; ++r) {
      int row = m0 + 16*w + q*4 + r;
      out[(size_t)row*768 + c] = acc[ns][r] + bv;
    }
  }
}

// ---------------------------------------------------------------------------
extern "C" void kernel_launch(void* const* d_in, const int* in_sizes, int n_in,
                              void* d_out, int out_size, void* d_ws, size_t ws_size,
                              hipStream_t stream)
{
  (void)out_size;

  static const int dict_sig[9] = {4718592,393216,393216,589824,589824,768,49152,512,512};
  bool is_dict = (n_in == 9);
  for (int i = 0; i < 9 && i < n_in; ++i)
    if (in_sizes[i] != dict_sig[i]) is_dict = false;

  const float *x, *Qw_w, *Kw_w, *Vw_w, *Ow_w, *out_b, *relKw, *rwb, *rrb;
  if (is_dict) {
    x     = (const float*)d_in[0];  Qw_w  = (const float*)d_in[1];
    Kw_w  = (const float*)d_in[2];  Vw_w  = (const float*)d_in[3];
    Ow_w  = (const float*)d_in[4];  out_b = (const float*)d_in[5];
    relKw = (const float*)d_in[6];  rwb   = (const float*)d_in[7];
    rrb   = (const float*)d_in[8];
  } else {
    const float* p393[2] = {nullptr,nullptr}; int n393 = 0;
    const float* p589[2] = {nullptr,nullptr}; int n589 = 0;
    const float* p512[2] = {nullptr,nullptr}; int n512 = 0;
    const float *px = nullptr, *prel = nullptr, *pb = nullptr;
    for (int i = 0; i < n_in; ++i) {
      const float* p = (const float*)d_in[i];
      switch (in_sizes[i]) {
        case 4718592: px = p; break;
        case 49152:   prel = p; break;
        case 768:     pb = p; break;
        case 393216:  if (n393 < 2) p393[n393++] = p; break;
        case 589824:  if (n589 < 2) p589[n589++] = p; break;
        case 512:     if (n512 < 2) p512[n512++] = p; break;
        default: break;
      }
    }
    x = px; relKw = prel; out_b = pb;
    Qw_w = p393[0]; Kw_w = p393[1];
    Vw_w = p589[0]; Ow_w = p589[1];
    rwb  = p512[0]; rrb  = p512[1];
  }

  float* out = (float*)d_out;

  char* ws = (char*)d_ws;
  size_t off = 0;
  auto alloc = [&](size_t bytes) -> void* {
    void* p = ws + off;
    off += (bytes + 255) & ~(size_t)255;
    return p;
  };

  float* gmax  = (float*)alloc(256);
  u16*   WtQKV = (u16*)  alloc((size_t)1792*768*2);   // 2.75 MB
  u16*   WtOut = (u16*)  alloc((size_t)768*768*2);    // 1.18 MB
  u16*   rK    = (u16*)  alloc((size_t)8*NPOSP*64*2); // 3 MB
  u16*   Qb    = (u16*)  alloc((size_t)32*LQ*64*2);   // 6.3 MB
  u16*   Kc    = (u16*)  alloc((size_t)32*LQ*64*2);   // 6.3 MB
  u16*   Vt    = (u16*)  alloc((size_t)32*96*LQ*2);   // 9.4 MB
  u16*   xb    = (u16*)  alloc((size_t)6144*768*2);   // 9.4 MB
  u16*   attnO = xb;  // alias: xb dead after qkv_gemm

  // pick nz by workspace headroom (partials = nz*(9.44 MB + 0.39 MB))
  size_t base_off = off;
  auto need = [&](int nzv) -> size_t {
    size_t o = base_off;
    o += (((size_t)nzv*32*LQ*96*2) + 255) & ~(size_t)255;
    o += (((size_t)nzv*32*LQ*2*4) + 255) & ~(size_t)255;
    return o;
  };
  int nz = 1;
  if (ws_size >= need(4)) nz = 4;
  else if (ws_size >= need(2)) nz = 2;
  u16*   Opart = nullptr; float* ml = nullptr;
  if (nz > 1) {
    Opart = (u16*)  alloc((size_t)nz*32*LQ*96*2);
    ml    = (float*)alloc((size_t)nz*32*LQ*2*4);
  }

  cvt_x      <<<dim3(4608), dim3(256), 0, stream>>>(x, xb);
  transpose_w<<<dim3(480),  dim3(256), 0, stream>>>(Qw_w, Kw_w, Vw_w, Ow_w, WtQKV, WtOut);
  gamma_max_k<<<dim3(16),   dim3(256), 0, stream>>>(gmax);
  rk_k       <<<dim3(NPOSP),dim3(256), 0, stream>>>(gmax, relKw, rK);
  qkv_gemm   <<<dim3(28,96),dim3(256), 0, stream>>>(xb, WtQKV, Qb, Kc, Vt);
  attn_k     <<<dim3(384*nz),dim3(512), 0, stream>>>(Qb, Kc, Vt, rK, rwb, rrb,
                                                     attnO, Opart, ml, nz);
  if (nz > 1)
    combine_k<<<dim3(18432), dim3(256), 0, stream>>>(Opart, ml, attnO, nz);
  out_gemm   <<<dim3(12,96),dim3(256), 0, stream>>>(attnO, WtOut, out_b, out);
}